// Round 20
// baseline (509.086 us; speedup 1.0000x reference)
//
#include <hip/hip_runtime.h>
#include <hip/hip_bf16.h>
#include <math.h>

#define F_IN 200
#define HDIM 64
#define NPG  400
#define EPG  6400
#define KSEL 200   // NPG/2
#define YST  66    // padded LDS row stride (floats) for H slice

typedef __attribute__((ext_vector_type(4))) float f32x4;
typedef __attribute__((ext_vector_type(8))) short s16x8;

__device__ __forceinline__ void gload_lds16(const void* g, void* l) {
    __builtin_amdgcn_global_load_lds(
        (const __attribute__((address_space(1))) void*)g,
        (__attribute__((address_space(3))) void*)l, 16, 0, 0);
}

// RNE float -> bf16 bits
__device__ __forceinline__ unsigned int bf16_rne(float x) {
    unsigned int b = __float_as_uint(x);
    return (b + 0x7FFFu + ((b >> 16) & 1u)) >> 16;
}

// split x into bf16 hi + bf16 lo (x ~= hi + lo, rel err ~2^-17)
__device__ __forceinline__ void split8(f32x4 v0, f32x4 v1, s16x8& h, s16x8& l) {
    float x[8] = {v0.x, v0.y, v0.z, v0.w, v1.x, v1.y, v1.z, v1.w};
#pragma unroll
    for (int j = 0; j < 8; j++) {
        unsigned int hb = bf16_rne(x[j]);
        float hf = __uint_as_float(hb << 16);
        float r = x[j] - hf;
        unsigned int lb = bf16_rne(r);
        h[j] = (short)hb;
        l[j] = (short)lb;
    }
}

// ---------------- pack W ([K,64]|[K,64] fp32) -> fragment-ordered bf16 pairs --
__global__ void pack_wf(const float* __restrict__ Wl, const float* __restrict__ Wr,
                        short* __restrict__ WF, int K, int KC) {
    int idx = blockIdx.x * blockDim.x + threadIdx.x;
    if (idx >= KC * 4096) return;
    int j    = idx & 7;
    int lane = (idx >> 3) & 63;
    int nf   = (idx >> 9) & 7;
    int kc   = idx >> 12;
    int k = kc * 32 + (lane >> 4) * 8 + j;
    int n = nf * 16 + (lane & 15);
    float v = 0.f;
    if (k < K) v = (n < 64) ? Wl[k * 64 + n] : Wr[k * 64 + (n - 64)];
    unsigned int hb = bf16_rne(v);
    float hf = __uint_as_float(hb << 16);
    unsigned int lb = bf16_rne(v - hf);
    WF[(size_t)((kc * 8 + nf) * 2 + 0) * 512 + lane * 8 + j] = (short)hb;
    WF[(size_t)((kc * 8 + nf) * 2 + 1) * 512 + lane * 8 + j] = (short)lb;
}

// ---------------- pack combine-W: [Wl;Wr] (K=128, 4 n-frags) ----------------
__global__ void pack_wf4(const float* __restrict__ Wl, const float* __restrict__ Wr,
                         short* __restrict__ WF) {
    int idx = blockIdx.x * blockDim.x + threadIdx.x;
    if (idx >= 4 * 2048) return;                 // 4 kc x 4 nf x 512
    int j    = idx & 7;
    int lane = (idx >> 3) & 63;
    int nf   = (idx >> 9) & 3;
    int kc   = idx >> 11;
    int k = kc * 32 + (lane >> 4) * 8 + j;
    int n = nf * 16 + (lane & 15);
    float v = (k < 64) ? Wl[k * 64 + n] : Wr[(k - 64) * 64 + n];
    unsigned int hb = bf16_rne(v);
    float hf = __uint_as_float(hb << 16);
    unsigned int lb = bf16_rne(v - hf);
    WF[(size_t)((kc * 4 + nf) * 2 + 0) * 512 + lane * 8 + j] = (short)hb;
    WF[(size_t)((kc * 4 + nf) * 2 + 1) * 512 + lane * 8 + j] = (short)lb;
}

// ---------------- layer-1 MFMA GEMM (R11-proven) ----------------------------
template <int K, int LDX, int KC, int TAIL>
__global__ __launch_bounds__(256) void gemm_lds(const float* __restrict__ X,
                                                const short* __restrict__ WF,
                                                float* __restrict__ O) {
    __shared__ float Xs[2][128 * 32];    // 2 x 16 KB
    __shared__ short Ws[2][8 * 2 * 512]; // 2 x 16 KB
    const int tid  = threadIdx.x;
    const int lane = tid & 63;
    const int wave = tid >> 6;
    const size_t rowbase = (size_t)blockIdx.x * 128;
    const f32x4 zero4 = (f32x4){0.f, 0.f, 0.f, 0.f};

    const int srow_off = wave * 32 + (lane >> 3);
    const int sbyte    = 16 * ((lane & 7) ^ (lane >> 3));

#define DMA_CHUNK(b, kc_) {                                                      \
    _Pragma("unroll")                                                            \
    for (int j = 0; j < 4; j++) {                                                \
        const char* xsrc = (const char*)X +                                      \
            (rowbase + srow_off + j * 8) * (size_t)(LDX * 4) + (kc_) * 128 + sbyte; \
        gload_lds16(xsrc, (char*)&Xs[b][0] + wave * 4096 + j * 1024);            \
        const short* wsrc = WF + (size_t)(kc_) * 8192 + wave * 2048 + j * 512 + lane * 8; \
        gload_lds16(wsrc, (char*)&Ws[b][0] + wave * 4096 + j * 1024);            \
    } }

    f32x4 acc[2][8];
#pragma unroll
    for (int m = 0; m < 2; m++)
#pragma unroll
        for (int nf = 0; nf < 8; nf++) acc[m][nf] = zero4;

    DMA_CHUNK(0, 0);
    __syncthreads();

    for (int kc = 0; kc < KC; kc++) {
        const int b = kc & 1;
        if (kc + 1 < KC) DMA_CHUNK(b ^ 1, kc + 1);

        s16x8 ah[2], al[2];
#pragma unroll
        for (int m = 0; m < 2; m++) {
            const int lr = wave * 32 + m * 16 + (lane & 15);
            const int g0 = (lane >> 4) * 2;
            f32x4 v0 = *(const f32x4*)&Xs[b][lr * 32 + 4 * (g0 ^ (lane & 7))];
            f32x4 v1 = *(const f32x4*)&Xs[b][lr * 32 + 4 * ((g0 + 1) ^ (lane & 7))];
            split8(v0, v1, ah[m], al[m]);
        }
#pragma unroll
        for (int nf = 0; nf < 8; nf++) {
            s16x8 wh = *(const s16x8*)&Ws[b][(nf * 2 + 0) * 512 + lane * 8];
            s16x8 wl = *(const s16x8*)&Ws[b][(nf * 2 + 1) * 512 + lane * 8];
#pragma unroll
            for (int m = 0; m < 2; m++) {
                acc[m][nf] = __builtin_amdgcn_mfma_f32_16x16x32_bf16(ah[m], wh, acc[m][nf], 0, 0, 0);
                acc[m][nf] = __builtin_amdgcn_mfma_f32_16x16x32_bf16(al[m], wh, acc[m][nf], 0, 0, 0);
                acc[m][nf] = __builtin_amdgcn_mfma_f32_16x16x32_bf16(ah[m], wl, acc[m][nf], 0, 0, 0);
            }
        }
        __syncthreads();
    }
#undef DMA_CHUNK

    if constexpr (TAIL > 0) {
        s16x8 ah[2], al[2];
#pragma unroll
        for (int m = 0; m < 2; m++) {
            const size_t row = rowbase + wave * 32 + m * 16 + (lane & 15);
            const int k0 = KC * 32 + (lane >> 4) * 8;
            f32x4 v0 = (k0 + 4 <= K) ? *(const f32x4*)&X[row * (size_t)LDX + k0] : zero4;
            f32x4 v1 = (k0 + 8 <= K) ? *(const f32x4*)&X[row * (size_t)LDX + k0 + 4] : zero4;
            split8(v0, v1, ah[m], al[m]);
        }
#pragma unroll
        for (int nf = 0; nf < 8; nf++) {
            s16x8 wh = *(const s16x8*)&WF[(size_t)((KC * 8 + nf) * 2 + 0) * 512 + lane * 8];
            s16x8 wl = *(const s16x8*)&WF[(size_t)((KC * 8 + nf) * 2 + 1) * 512 + lane * 8];
#pragma unroll
            for (int m = 0; m < 2; m++) {
                acc[m][nf] = __builtin_amdgcn_mfma_f32_16x16x32_bf16(ah[m], wh, acc[m][nf], 0, 0, 0);
                acc[m][nf] = __builtin_amdgcn_mfma_f32_16x16x32_bf16(al[m], wh, acc[m][nf], 0, 0, 0);
                acc[m][nf] = __builtin_amdgcn_mfma_f32_16x16x32_bf16(ah[m], wl, acc[m][nf], 0, 0, 0);
            }
        }
    }

    float* cs0 = &Xs[0][wave * 1024];
    float* cs1 = &Xs[1][wave * 1024];
#pragma unroll
    for (int m = 0; m < 2; m++) {
        const int scol = lane & 15;
        const int srow = (lane >> 4) * 4;
#pragma unroll
        for (int nf = 0; nf < 8; nf++)
#pragma unroll
            for (int r = 0; r < 4; r++) {
                int cr = srow + r;
                float* p = (cr < 8) ? cs0 + cr * 128 : cs1 + (cr - 8) * 128;
                p[nf * 16 + scol] = acc[m][nf][r];
            }
#pragma unroll
        for (int ps = 0; ps < 8; ps++) {
            int row = ps * 2 + (lane >> 5);
            const float* p = (row < 8) ? cs0 + row * 128 : cs1 + (row - 8) * 128;
            f32x4 v = *(const f32x4*)&p[(lane & 31) * 4];
            *(f32x4*)&O[(rowbase + wave * 32 + m * 16 + row) * 128 + (lane & 31) * 4] = v;
        }
    }
}

// ------- fused m-form layer: P = relu([mean_agg(H)|H] @ Wc + b) + H ----------
// One block per graph, 512 thr (8 waves). H slice staged in LDS (stride 66).
// M computed DIRECTLY in MFMA A-fragment layout in registers: lane l of frag f
// accumulates M[f*16+(l&15)][dims (l>>4)*8 + 0..7 (+32)] over the node's
// in-edges (csr/deg/invdeg staged in LDS). W staged once per block (amortized
// over 25 frags). Epilogue reads resid=H from LDS, fused bias/relu.
__global__ __launch_bounds__(512) void layer_m(
    const float* __restrict__ H,
    const short* __restrict__ WFc,           // 16384 shorts (4kc x 4nf x 2 x 512)
    const float* __restrict__ bias,
    const int* __restrict__ csr_src, const int* __restrict__ rowptr,
    const int* __restrict__ degs, const float* __restrict__ invdeg,
    float* __restrict__ P)
{
    __shared__ float y[NPG * YST];           // 105600 B
    __shared__ unsigned short csrs[EPG];     // 12800 B
    __shared__ short Ws[16384];              // 32768 B
    __shared__ int rps[NPG];                 // 1600 B
    __shared__ float invd[NPG];              // 1600 B
    __shared__ unsigned short dgs[NPG];      // 800 B
    __shared__ float bs[64];                 // 256 B   (total 155424 B)

    const int g = blockIdx.x, tid = threadIdx.x;
    const int lane = tid & 63, wave = tid >> 6;
    const int nodebase = g * NPG, ebase = g * EPG;

    // ---- stage everything (one barrier) ----
    for (int idx = tid; idx < NPG * 16; idx += 512) {
        int node = idx >> 4, c4 = (idx & 15) * 4;
        *(float4*)&y[node * YST + c4] =
            *(const float4*)&H[(size_t)(nodebase + node) * 64 + c4];
    }
    for (int e = tid; e < EPG; e += 512)
        csrs[e] = (unsigned short)csr_src[ebase + e];
    for (int i = tid; i < NPG; i += 512) {
        rps[i]  = rowptr[nodebase + i];
        invd[i] = invdeg[nodebase + i];
        dgs[i]  = (unsigned short)degs[nodebase + i];
    }
    for (int i = tid; i < 2048; i += 512)
        *(s16x8*)&Ws[i * 8] = *(const s16x8*)&WFc[i * 8];
    if (tid < 64) bs[tid] = bias[tid];
    __syncthreads();

    const int kq = (lane >> 4) * 8;          // dim octet base (0,8,16,24)
    const f32x4 zero4 = (f32x4){0.f, 0.f, 0.f, 0.f};

    for (int f = wave; f < 25; f += 8) {
        const int nl = f * 16 + (lane & 15); // local node (A-frag row)
        // ---- M accumulation in fragment layout ----
        f32x4 m0a = zero4, m0b = zero4, m1a = zero4, m1b = zero4;
        {
            const int start = rps[nl];
            const int dg = dgs[nl];
            int j = 0;
            for (; j + 2 <= dg; j += 2) {
                int s0 = csrs[start + j];
                int s1 = csrs[start + j + 1];
                const float* y0 = &y[s0 * YST];
                const float* y1 = &y[s1 * YST];
                m0a += *(const f32x4*)&y0[kq]      + *(const f32x4*)&y1[kq];
                m0b += *(const f32x4*)&y0[kq + 4]  + *(const f32x4*)&y1[kq + 4];
                m1a += *(const f32x4*)&y0[32 + kq] + *(const f32x4*)&y1[32 + kq];
                m1b += *(const f32x4*)&y0[32 + kq + 4] + *(const f32x4*)&y1[32 + kq + 4];
            }
            for (; j < dg; j++) {
                int s = csrs[start + j];
                const float* yr = &y[s * YST];
                m0a += *(const f32x4*)&yr[kq];
                m0b += *(const f32x4*)&yr[kq + 4];
                m1a += *(const f32x4*)&yr[32 + kq];
                m1b += *(const f32x4*)&yr[32 + kq + 4];
            }
            const float inv = invd[nl];
            m0a *= inv; m0b *= inv; m1a *= inv; m1b *= inv;
        }
        // ---- A fragments: kc0,1 = M halves; kc2,3 = H halves (from LDS) ----
        s16x8 ah[4], al[4];
        split8(m0a, m0b, ah[0], al[0]);
        split8(m1a, m1b, ah[1], al[1]);
        {
            const float* hr = &y[nl * YST];
            f32x4 h0a = *(const f32x4*)&hr[kq];
            f32x4 h0b = *(const f32x4*)&hr[kq + 4];
            f32x4 h1a = *(const f32x4*)&hr[32 + kq];
            f32x4 h1b = *(const f32x4*)&hr[32 + kq + 4];
            split8(h0a, h0b, ah[2], al[2]);
            split8(h1a, h1b, ah[3], al[3]);
        }
        // ---- MFMA: 4 kc x 4 nf x 3 ----
        f32x4 acc[4];
#pragma unroll
        for (int nf = 0; nf < 4; nf++) acc[nf] = zero4;
#pragma unroll
        for (int kc = 0; kc < 4; kc++) {
#pragma unroll
            for (int nf = 0; nf < 4; nf++) {
                s16x8 wh = *(const s16x8*)&Ws[((kc * 4 + nf) * 2 + 0) * 512 + lane * 8];
                s16x8 wl = *(const s16x8*)&Ws[((kc * 4 + nf) * 2 + 1) * 512 + lane * 8];
                acc[nf] = __builtin_amdgcn_mfma_f32_16x16x32_bf16(ah[kc], wh, acc[nf], 0, 0, 0);
                acc[nf] = __builtin_amdgcn_mfma_f32_16x16x32_bf16(al[kc], wh, acc[nf], 0, 0, 0);
                acc[nf] = __builtin_amdgcn_mfma_f32_16x16x32_bf16(ah[kc], wl, acc[nf], 0, 0, 0);
            }
        }
        // ---- epilogue: D row=(lane>>4)*4+r, col=nf*16+(lane&15); resid from LDS
        {
            const int orow0 = f * 16 + (lane >> 4) * 4;
            const int oc = lane & 15;
#pragma unroll
            for (int nf = 0; nf < 4; nf++) {
                const int col = nf * 16 + oc;
                const float bv = bs[col];
#pragma unroll
                for (int r = 0; r < 4; r++) {
                    const int lr = orow0 + r;
                    float v = fmaxf(acc[nf][r] + bv, 0.f) + y[lr * YST + col];
                    P[(size_t)(nodebase + lr) * 64 + col] = v;
                }
            }
        }
    }
}

// ---------------- CSR build: one block per graph ----------------
__global__ __launch_bounds__(256) void csr_build(
    const int* __restrict__ esrc, const int* __restrict__ edst,
    int* __restrict__ csr_src, int* __restrict__ rowptr,
    int* __restrict__ degs, float* __restrict__ invdeg)
{
    __shared__ int cnt[NPG];
    __shared__ int off[NPG];
    __shared__ int cur[NPG];
    const int g = blockIdx.x, tid = threadIdx.x;
    const int ebase = g * EPG, nodebase = g * NPG;
    for (int i = tid; i < NPG; i += 256) cnt[i] = 0;
    __syncthreads();
    for (int e = tid; e < EPG; e += 256)
        atomicAdd(&cnt[edst[ebase + e] - nodebase], 1);
    __syncthreads();
    if (tid == 0) {
        int run = 0;
        for (int i = 0; i < NPG; i++) { off[i] = run; run += cnt[i]; }
    }
    __syncthreads();
    for (int i = tid; i < NPG; i += 256) {
        cur[i] = off[i];
        rowptr[nodebase + i] = off[i];
        degs[nodebase + i] = cnt[i];
        invdeg[nodebase + i] = 1.f / fmaxf((float)cnt[i], 1.f);
    }
    __syncthreads();
    for (int e = tid; e < EPG; e += 256) {
        int ld = edst[ebase + e] - nodebase;
        int p = atomicAdd(&cur[ld], 1);
        csr_src[ebase + p] = esrc[ebase + e] - nodebase;  // local src
    }
}

// ---------------- layer-1 aggregate+combine (reads A [N,128]) ----------------
__global__ __launch_bounds__(1024) void agg_lds(
    const float* __restrict__ A,
    const int* __restrict__ csr_src, const int* __restrict__ rowptr,
    const int* __restrict__ degs, const float* __restrict__ invdeg,
    const float* __restrict__ bias,
    float* __restrict__ Xout)
{
    __shared__ float y[NPG * 64];     // 102400 B
    __shared__ int   csr_l[EPG];      // 25600 B
    const int g = blockIdx.x, tid = threadIdx.x;
    const int ebase = g * EPG, nodebase = g * NPG;

    for (int idx = tid; idx < NPG * 16; idx += 1024) {
        int node = idx >> 4, c4 = (idx & 15) * 4;
        *(float4*)&y[node * 64 + c4] =
            *(const float4*)&A[(size_t)(nodebase + node) * 128 + c4];
    }
    for (int e = tid; e < EPG; e += 1024) csr_l[e] = csr_src[ebase + e];
    __syncthreads();

    const int wave = tid >> 6, lane = tid & 63;
    for (int node = wave; node < NPG; node += 16) {
        const int start = rowptr[nodebase + node];
        const int dg = degs[nodebase + node];
        float acc = 0.f;
        int j = 0;
        for (; j + 4 <= dg; j += 4) {
            int s0 = csr_l[start + j];
            int s1 = csr_l[start + j + 1];
            int s2 = csr_l[start + j + 2];
            int s3 = csr_l[start + j + 3];
            acc += y[s0 * 64 + lane] + y[s1 * 64 + lane]
                 + y[s2 * 64 + lane] + y[s3 * 64 + lane];
        }
        for (; j < dg; j++) acc += y[csr_l[start + j] * 64 + lane];

        float v = acc * invdeg[nodebase + node] + bias[lane]
                + A[(size_t)(nodebase + node) * 128 + 64 + lane];
        Xout[(size_t)(nodebase + node) * 64 + lane] = fmaxf(v, 0.f);
    }
}

// ------- score+topk+pool+classifier, LDS-staged (R15-proven) ----------------
__global__ __launch_bounds__(1024) void score_pool3(
    const float* __restrict__ X3,
    const int* __restrict__ esrc, const int* __restrict__ edst,
    const float* __restrict__ Wpr, const float* __restrict__ bpr,
    const float* __restrict__ Wpo,
    const float* __restrict__ Wlin, const float* __restrict__ blin,
    float* __restrict__ out)
{
    __shared__ float y[NPG * 64];        // 102400 B (X3 slice)
    __shared__ float t0s[NPG], ss[NPG], wsel[NPG];
    __shared__ float wprs[64], wpos[64];
    __shared__ float pp[16 * 64];
    __shared__ float pooled[64];
    __shared__ float lgs[2];
    const int g = blockIdx.x, tid = threadIdx.x;
    const int nodebase = g * NPG, ebase = g * EPG;

    if (tid < 64) { wprs[tid] = Wpr[tid]; wpos[tid] = Wpo[tid]; }
    for (int idx = tid; idx < NPG * 16; idx += 1024) {
        int node = idx >> 4, c4 = (idx & 15) * 4;
        *(float4*)&y[node * 64 + c4] =
            *(const float4*)&X3[(size_t)(nodebase + node) * 64 + c4];
    }
    __syncthreads();

    if (tid < NPG) {
        float a0 = 0.f, a1 = 0.f;
        const float* yr = &y[tid * 64];
#pragma unroll
        for (int i = 0; i < 64; i++) {
            int d = (tid + i) & 63;
            float v = yr[d];
            a0 += v * wprs[d];
            a1 += v * wpos[d];
        }
        t0s[tid] = a0;
        ss[tid] = bpr[0] + a1;
    }
    __syncthreads();
    for (int e = tid; e < EPG; e += 1024) {
        int ls = esrc[ebase + e] - nodebase;
        int ld = edst[ebase + e] - nodebase;
        atomicAdd(&ss[ld], t0s[ls]);
    }
    __syncthreads();
    if (tid < NPG) {
        float si = ss[tid];
        int cnt = 0;
        for (int j = 0; j < NPG; j++) {
            float sj = ss[j];
            cnt += (sj > si) || (sj == si && j < tid);
        }
        wsel[tid] = (cnt < KSEL) ? tanhf(si) * (1.f / KSEL) : 0.f;
    }
    __syncthreads();
    {
        const int d = tid & 63, part = tid >> 6;
        float a = 0.f;
        for (int i = part * 25; i < part * 25 + 25; i++)
            a += wsel[i] * y[i * 64 + d];
        pp[part * 64 + d] = a;
    }
    __syncthreads();
    if (tid < 64) {
        float s = 0.f;
#pragma unroll
        for (int i = 0; i < 16; i++) s += pp[i * 64 + tid];
        pooled[tid] = s;
    }
    __syncthreads();
    if (tid < 2) {
        float l = blin[tid];
        for (int d = 0; d < 64; d++) l += pooled[d] * Wlin[d * 2 + tid];
        lgs[tid] = l;
    }
    __syncthreads();
    if (tid < 2) {
        float m = fmaxf(lgs[0], lgs[1]);
        float lse = m + logf(expf(lgs[0] - m) + expf(lgs[1] - m));
        out[g * 2 + tid] = lgs[tid] - lse;
    }
}

extern "C" void kernel_launch(void* const* d_in, const int* in_sizes, int n_in,
                              void* d_out, int out_size, void* d_ws, size_t ws_size,
                              hipStream_t stream) {
    const float* x    = (const float*)d_in[0];
    const int*   eidx = (const int*)d_in[1];
    const float* W1l  = (const float*)d_in[3];
    const float* W1r  = (const float*)d_in[4];
    const float* b1   = (const float*)d_in[5];
    const float* W2l  = (const float*)d_in[6];
    const float* W2r  = (const float*)d_in[7];
    const float* b2   = (const float*)d_in[8];
    const float* W3l  = (const float*)d_in[9];
    const float* W3r  = (const float*)d_in[10];
    const float* b3   = (const float*)d_in[11];
    const float* Wpr  = (const float*)d_in[12];
    const float* bpr  = (const float*)d_in[13];
    const float* Wpo  = (const float*)d_in[14];
    const float* Wlin = (const float*)d_in[15];
    const float* blin = (const float*)d_in[16];

    const int N = in_sizes[0] / F_IN;       // 204800
    const int E = in_sizes[1] / 2;          // 3276800
    const int B = N / NPG;                  // 512
    const int* esrc = eidx;
    const int* edst = eidx + E;

    float* ws = (float*)d_ws;
    float* A      = ws;                                  // [N,128] layer-1 yz
    float* P0     = A + (size_t)N * 128;                 // [N,64]
    float* P1     = P0 + (size_t)N * 64;                 // [N,64]
    float* invdeg = P1 + (size_t)N * 64;                 // [N]
    short* WF1    = (short*)(invdeg + N);                // 7*8*2*512 shorts
    short* WFc2   = WF1 + 57344;                         // 4*4*2*512 shorts
    short* WFc3   = WFc2 + 16384;
    int*   csr    = (int*)(WFc3 + 16384);                // [E] local src by dst
    int*   rowptr = csr + E;                             // [N]
    int*   degs   = rowptr + N;                          // [N]

    pack_wf<<<(7 * 4096 + 255) / 256, 256, 0, stream>>>(W1l, W1r, WF1, 200, 7);
    pack_wf4<<<(4 * 2048 + 255) / 256, 256, 0, stream>>>(W2l, W2r, WFc2);
    pack_wf4<<<(4 * 2048 + 255) / 256, 256, 0, stream>>>(W3l, W3r, WFc3);

    // CSR once (shared by all layers)
    csr_build<<<B, 256, 0, stream>>>(esrc, edst, csr, rowptr, degs, invdeg);

    // layer 1: yz = x @ [W1l|W1r] -> A; x1 = relu(agg(y)+b+z) -> P0
    gemm_lds<200, 200, 6, 8><<<N / 128, 256, 0, stream>>>(x, WF1, A);
    agg_lds<<<B, 1024, 0, stream>>>(A, csr, rowptr, degs, invdeg, b1, P0);

    // layer 2 (fused m-form): x2 = relu([mean_agg(P0)|P0]@Wc2 + b2) + P0 -> P1
    layer_m<<<B, 512, 0, stream>>>(P0, WFc2, b2, csr, rowptr, degs, invdeg, P1);

    // layer 3 (fused m-form): x3 = relu([mean_agg(P1)|P1]@Wc3 + b3) + P1 -> P0
    layer_m<<<B, 512, 0, stream>>>(P1, WFc3, b3, csr, rowptr, degs, invdeg, P0);

    // score + top-k + pool + classifier (LDS-staged)
    score_pool3<<<B, 1024, 0, stream>>>(P0, esrc, edst,
                                        Wpr, bpr, Wpo, Wlin, blin,
                                        (float*)d_out);
}

// Round 21
// 418.982 us; speedup vs baseline: 1.2151x; 1.2151x over previous
//
#include <hip/hip_runtime.h>
#include <hip/hip_bf16.h>
#include <math.h>

#define F_IN 200
#define HDIM 64
#define NPG  400
#define EPG  6400
#define KSEL 200   // NPG/2

typedef __attribute__((ext_vector_type(4))) float f32x4;
typedef __attribute__((ext_vector_type(8))) short s16x8;
typedef __attribute__((ext_vector_type(4))) unsigned short u16x4;
typedef __attribute__((ext_vector_type(8))) unsigned short u16x8;

__device__ __forceinline__ void gload_lds16(const void* g, void* l) {
    __builtin_amdgcn_global_load_lds(
        (const __attribute__((address_space(1))) void*)g,
        (__attribute__((address_space(3))) void*)l, 16, 0, 0);
}

// RNE float -> bf16 bits
__device__ __forceinline__ unsigned int bf16_rne(float x) {
    unsigned int b = __float_as_uint(x);
    return (b + 0x7FFFu + ((b >> 16) & 1u)) >> 16;
}
__device__ __forceinline__ float frombf(unsigned short u) {
    return __uint_as_float(((unsigned int)u) << 16);
}

// split x into bf16 hi + bf16 lo (x ~= hi + lo, rel err ~2^-17)
__device__ __forceinline__ void split8(f32x4 v0, f32x4 v1, s16x8& h, s16x8& l) {
    float x[8] = {v0.x, v0.y, v0.z, v0.w, v1.x, v1.y, v1.z, v1.w};
#pragma unroll
    for (int j = 0; j < 8; j++) {
        unsigned int hb = bf16_rne(x[j]);
        float hf = __uint_as_float(hb << 16);
        float r = x[j] - hf;
        unsigned int lb = bf16_rne(r);
        h[j] = (short)hb;
        l[j] = (short)lb;
    }
}

// ---------------- pack W ([K,64]|[K,64] fp32) -> fragment-ordered bf16 pairs --
__global__ void pack_wf(const float* __restrict__ Wl, const float* __restrict__ Wr,
                        short* __restrict__ WF, int K, int KC) {
    int idx = blockIdx.x * blockDim.x + threadIdx.x;
    if (idx >= KC * 4096) return;
    int j    = idx & 7;
    int lane = (idx >> 3) & 63;
    int nf   = (idx >> 9) & 7;
    int kc   = idx >> 12;
    int k = kc * 32 + (lane >> 4) * 8 + j;
    int n = nf * 16 + (lane & 15);
    float v = 0.f;
    if (k < K) v = (n < 64) ? Wl[k * 64 + n] : Wr[k * 64 + (n - 64)];
    unsigned int hb = bf16_rne(v);
    float hf = __uint_as_float(hb << 16);
    unsigned int lb = bf16_rne(v - hf);
    WF[(size_t)((kc * 8 + nf) * 2 + 0) * 512 + lane * 8 + j] = (short)hb;
    WF[(size_t)((kc * 8 + nf) * 2 + 1) * 512 + lane * 8 + j] = (short)lb;
}

// ---------------- pack combine-W: [Wl;Wr] (K=128, 4 n-frags) ----------------
__global__ void pack_wf4(const float* __restrict__ Wl, const float* __restrict__ Wr,
                         short* __restrict__ WF) {
    int idx = blockIdx.x * blockDim.x + threadIdx.x;
    if (idx >= 4 * 2048) return;                 // 4 kc x 4 nf x 512
    int j    = idx & 7;
    int lane = (idx >> 3) & 63;
    int nf   = (idx >> 9) & 3;
    int kc   = idx >> 11;
    int k = kc * 32 + (lane >> 4) * 8 + j;
    int n = nf * 16 + (lane & 15);
    float v = (k < 64) ? Wl[k * 64 + n] : Wr[(k - 64) * 64 + n];
    unsigned int hb = bf16_rne(v);
    float hf = __uint_as_float(hb << 16);
    unsigned int lb = bf16_rne(v - hf);
    WF[(size_t)((kc * 4 + nf) * 2 + 0) * 512 + lane * 8 + j] = (short)hb;
    WF[(size_t)((kc * 4 + nf) * 2 + 1) * 512 + lane * 8 + j] = (short)lb;
}

// ---------------- layer-1 MFMA GEMM (R11-proven; bf16 output) ----------------
template <int K, int LDX, int KC, int TAIL>
__global__ __launch_bounds__(256) void gemm_lds(const float* __restrict__ X,
                                                const short* __restrict__ WF,
                                                unsigned short* __restrict__ O) {
    __shared__ float Xs[2][128 * 32];    // 2 x 16 KB
    __shared__ short Ws[2][8 * 2 * 512]; // 2 x 16 KB
    const int tid  = threadIdx.x;
    const int lane = tid & 63;
    const int wave = tid >> 6;
    const size_t rowbase = (size_t)blockIdx.x * 128;
    const f32x4 zero4 = (f32x4){0.f, 0.f, 0.f, 0.f};

    const int srow_off = wave * 32 + (lane >> 3);
    const int sbyte    = 16 * ((lane & 7) ^ (lane >> 3));

#define DMA_CHUNK(b, kc_) {                                                      \
    _Pragma("unroll")                                                            \
    for (int j = 0; j < 4; j++) {                                                \
        const char* xsrc = (const char*)X +                                      \
            (rowbase + srow_off + j * 8) * (size_t)(LDX * 4) + (kc_) * 128 + sbyte; \
        gload_lds16(xsrc, (char*)&Xs[b][0] + wave * 4096 + j * 1024);            \
        const short* wsrc = WF + (size_t)(kc_) * 8192 + wave * 2048 + j * 512 + lane * 8; \
        gload_lds16(wsrc, (char*)&Ws[b][0] + wave * 4096 + j * 1024);            \
    } }

    f32x4 acc[2][8];
#pragma unroll
    for (int m = 0; m < 2; m++)
#pragma unroll
        for (int nf = 0; nf < 8; nf++) acc[m][nf] = zero4;

    DMA_CHUNK(0, 0);
    __syncthreads();

    for (int kc = 0; kc < KC; kc++) {
        const int b = kc & 1;
        if (kc + 1 < KC) DMA_CHUNK(b ^ 1, kc + 1);

        s16x8 ah[2], al[2];
#pragma unroll
        for (int m = 0; m < 2; m++) {
            const int lr = wave * 32 + m * 16 + (lane & 15);
            const int g0 = (lane >> 4) * 2;
            f32x4 v0 = *(const f32x4*)&Xs[b][lr * 32 + 4 * (g0 ^ (lane & 7))];
            f32x4 v1 = *(const f32x4*)&Xs[b][lr * 32 + 4 * ((g0 + 1) ^ (lane & 7))];
            split8(v0, v1, ah[m], al[m]);
        }
#pragma unroll
        for (int nf = 0; nf < 8; nf++) {
            s16x8 wh = *(const s16x8*)&Ws[b][(nf * 2 + 0) * 512 + lane * 8];
            s16x8 wl = *(const s16x8*)&Ws[b][(nf * 2 + 1) * 512 + lane * 8];
#pragma unroll
            for (int m = 0; m < 2; m++) {
                acc[m][nf] = __builtin_amdgcn_mfma_f32_16x16x32_bf16(ah[m], wh, acc[m][nf], 0, 0, 0);
                acc[m][nf] = __builtin_amdgcn_mfma_f32_16x16x32_bf16(al[m], wh, acc[m][nf], 0, 0, 0);
                acc[m][nf] = __builtin_amdgcn_mfma_f32_16x16x32_bf16(ah[m], wl, acc[m][nf], 0, 0, 0);
            }
        }
        __syncthreads();
    }
#undef DMA_CHUNK

    if constexpr (TAIL > 0) {
        s16x8 ah[2], al[2];
#pragma unroll
        for (int m = 0; m < 2; m++) {
            const size_t row = rowbase + wave * 32 + m * 16 + (lane & 15);
            const int k0 = KC * 32 + (lane >> 4) * 8;
            f32x4 v0 = (k0 + 4 <= K) ? *(const f32x4*)&X[row * (size_t)LDX + k0] : zero4;
            f32x4 v1 = (k0 + 8 <= K) ? *(const f32x4*)&X[row * (size_t)LDX + k0 + 4] : zero4;
            split8(v0, v1, ah[m], al[m]);
        }
#pragma unroll
        for (int nf = 0; nf < 8; nf++) {
            s16x8 wh = *(const s16x8*)&WF[(size_t)((KC * 8 + nf) * 2 + 0) * 512 + lane * 8];
            s16x8 wl = *(const s16x8*)&WF[(size_t)((KC * 8 + nf) * 2 + 1) * 512 + lane * 8];
#pragma unroll
            for (int m = 0; m < 2; m++) {
                acc[m][nf] = __builtin_amdgcn_mfma_f32_16x16x32_bf16(ah[m], wh, acc[m][nf], 0, 0, 0);
                acc[m][nf] = __builtin_amdgcn_mfma_f32_16x16x32_bf16(al[m], wh, acc[m][nf], 0, 0, 0);
                acc[m][nf] = __builtin_amdgcn_mfma_f32_16x16x32_bf16(ah[m], wl, acc[m][nf], 0, 0, 0);
            }
        }
    }

    // epilogue: fp32 restage (proven), convert to bf16 on store (ushort4 = 8B/lane)
    float* cs0 = &Xs[0][wave * 1024];
    float* cs1 = &Xs[1][wave * 1024];
#pragma unroll
    for (int m = 0; m < 2; m++) {
        const int scol = lane & 15;
        const int srow = (lane >> 4) * 4;
#pragma unroll
        for (int nf = 0; nf < 8; nf++)
#pragma unroll
            for (int r = 0; r < 4; r++) {
                int cr = srow + r;
                float* p = (cr < 8) ? cs0 + cr * 128 : cs1 + (cr - 8) * 128;
                p[nf * 16 + scol] = acc[m][nf][r];
            }
#pragma unroll
        for (int ps = 0; ps < 8; ps++) {
            int row = ps * 2 + (lane >> 5);
            int col = (lane & 31) * 4;
            const float* p = (row < 8) ? cs0 + row * 128 : cs1 + (row - 8) * 128;
            f32x4 v = *(const f32x4*)&p[col];
            u16x4 o;
#pragma unroll
            for (int q = 0; q < 4; q++) o[q] = (unsigned short)bf16_rne(v[q]);
            *(u16x4*)&O[(rowbase + wave * 32 + m * 16 + row) * 128 + col] = o;
        }
    }
}

// ------- combine GEMM, single-shot (R16-proven) + T14 resid/bias prefetch ----
__global__ __launch_bounds__(256) void combine_ss(
    const float* __restrict__ M, const float* __restrict__ H,
    const short* __restrict__ WF, const float* __restrict__ bias,
    const float* __restrict__ resid, float* __restrict__ P)
{
    __shared__ float Xs[4][64 * 32];     // 4 x 8 KB
    __shared__ short Ws[4][4096];        // 4 x 8 KB
    const int tid  = threadIdx.x;
    const int lane = tid & 63;
    const int wave = tid >> 6;
    const size_t rowbase = (size_t)blockIdx.x * 64;

    // ---- T14: prefetch epilogue operands early ----
    f32x4 rr[4], bb;
    {
        const int col = (lane & 15) * 4;
        bb = *(const f32x4*)&bias[col];
#pragma unroll
        for (int i = 0; i < 4; i++) {
            int row = i * 4 + (lane >> 4);
            size_t grow = rowbase + wave * 16 + row;
            rr[i] = *(const f32x4*)&resid[grow * 64 + col];
        }
    }

    // ---- DMA all 4 chunks (wave-uniform srcbuf per chunk) ----
#pragma unroll
    for (int c = 0; c < 4; c++) {
        const float* srcbuf = (c < 2) ? M : H;      // wave-uniform select
#pragma unroll
        for (int i = 0; i < 2; i++) {
            int rr2 = i * 8 + (lane >> 3);
            int jj = (lane & 7) ^ (rr2 & 7);
            const char* src = (const char*)(srcbuf + (rowbase + wave * 16 + rr2) * 64)
                              + (c & 1) * 128 + jj * 16;
            gload_lds16(src, (char*)&Xs[c][0] + wave * 2048 + i * 1024 + lane * 16);
        }
#pragma unroll
        for (int t = 0; t < 2; t++) {
            int idx = t * 256 + tid;
            const short* wsrc = WF + (size_t)c * 4096 + idx * 8;
            gload_lds16(wsrc, (char*)&Ws[c][0] + idx * 16);
        }
    }
    __syncthreads();

    f32x4 acc[4];
#pragma unroll
    for (int nf = 0; nf < 4; nf++) acc[nf] = (f32x4){0.f, 0.f, 0.f, 0.f};

    const int r = lane & 15;
    const int j0 = (lane >> 4) * 2;
#pragma unroll
    for (int kc = 0; kc < 4; kc++) {
        const float* abase = &Xs[kc][wave * 512 + r * 32];
        f32x4 v0 = *(const f32x4*)&abase[((j0    ) ^ (r & 7)) * 4];
        f32x4 v1 = *(const f32x4*)&abase[((j0 + 1) ^ (r & 7)) * 4];
        s16x8 ah, al;
        split8(v0, v1, ah, al);
#pragma unroll
        for (int nf = 0; nf < 4; nf++) {
            s16x8 wh = *(const s16x8*)&Ws[kc][(nf * 2 + 0) * 512 + lane * 8];
            s16x8 wl = *(const s16x8*)&Ws[kc][(nf * 2 + 1) * 512 + lane * 8];
            acc[nf] = __builtin_amdgcn_mfma_f32_16x16x32_bf16(ah, wh, acc[nf], 0, 0, 0);
            acc[nf] = __builtin_amdgcn_mfma_f32_16x16x32_bf16(al, wh, acc[nf], 0, 0, 0);
            acc[nf] = __builtin_amdgcn_mfma_f32_16x16x32_bf16(ah, wl, acc[nf], 0, 0, 0);
        }
    }

    // ---- epilogue: wave-private restage, fused bias/relu/resid (prefetched) --
    {
        float* cs0 = &Xs[0][wave * 512];
        float* cs1 = &Xs[1][wave * 512];
        const int scol = lane & 15;
        const int srow = (lane >> 4) * 4;
#pragma unroll
        for (int nf = 0; nf < 4; nf++)
#pragma unroll
            for (int ri = 0; ri < 4; ri++) {
                int cr = srow + ri;
                float* p = (cr < 8) ? cs0 + cr * 64 : cs1 + (cr - 8) * 64;
                p[nf * 16 + scol] = acc[nf][ri];
            }
#pragma unroll
        for (int i = 0; i < 4; i++) {
            int row = i * 4 + (lane >> 4);
            int col = (lane & 15) * 4;
            const float* p = (row < 8) ? cs0 + row * 64 : cs1 + (row - 8) * 64;
            f32x4 v = *(const f32x4*)&p[col];
            size_t grow = rowbase + wave * 16 + row;
            f32x4 o;
#pragma unroll
            for (int q = 0; q < 4; q++) o[q] = fmaxf(v[q] + bb[q], 0.f) + rr[i][q];
            *(f32x4*)&P[grow * 64 + col] = o;
        }
    }
}

// ---------------- CSR build: one block per graph ----------------
__global__ __launch_bounds__(256) void csr_build(
    const int* __restrict__ esrc, const int* __restrict__ edst,
    int* __restrict__ csr_src, int* __restrict__ rowptr,
    int* __restrict__ degs, float* __restrict__ invdeg)
{
    __shared__ int cnt[NPG];
    __shared__ int off[NPG];
    __shared__ int cur[NPG];
    const int g = blockIdx.x, tid = threadIdx.x;
    const int ebase = g * EPG, nodebase = g * NPG;
    for (int i = tid; i < NPG; i += 256) cnt[i] = 0;
    __syncthreads();
    for (int e = tid; e < EPG; e += 256)
        atomicAdd(&cnt[edst[ebase + e] - nodebase], 1);
    __syncthreads();
    if (tid == 0) {
        int run = 0;
        for (int i = 0; i < NPG; i++) { off[i] = run; run += cnt[i]; }
    }
    __syncthreads();
    for (int i = tid; i < NPG; i += 256) {
        cur[i] = off[i];
        rowptr[nodebase + i] = off[i];
        degs[nodebase + i] = cnt[i];
        invdeg[nodebase + i] = 1.f / fmaxf((float)cnt[i], 1.f);
    }
    __syncthreads();
    for (int e = tid; e < EPG; e += 256) {
        int ld = edst[ebase + e] - nodebase;
        int p = atomicAdd(&cur[ld], 1);
        csr_src[ebase + p] = esrc[ebase + e] - nodebase;  // local src
    }
}

// ---------------- layer-1 aggregate+combine (reads bf16 A [N,128]) -----------
__global__ __launch_bounds__(1024) void agg_lds(
    const unsigned short* __restrict__ A,
    const int* __restrict__ csr_src, const int* __restrict__ rowptr,
    const int* __restrict__ degs, const float* __restrict__ invdeg,
    const float* __restrict__ bias,
    float* __restrict__ Xout)
{
    __shared__ float y[NPG * 64];     // 102400 B
    __shared__ int   csr_l[EPG];      // 25600 B
    const int g = blockIdx.x, tid = threadIdx.x;
    const int ebase = g * EPG, nodebase = g * NPG;

    // stage y-half (bf16 -> f32): 8 elems per thread-step
    for (int idx = tid; idx < NPG * 8; idx += 1024) {
        int node = idx >> 3, c8 = (idx & 7) * 8;
        u16x8 v = *(const u16x8*)&A[(size_t)(nodebase + node) * 128 + c8];
#pragma unroll
        for (int q = 0; q < 8; q++) y[node * 64 + c8 + q] = frombf(v[q]);
    }
    for (int e = tid; e < EPG; e += 1024) csr_l[e] = csr_src[ebase + e];
    __syncthreads();

    const int wave = tid >> 6, lane = tid & 63;
    for (int node = wave; node < NPG; node += 16) {
        const int start = rowptr[nodebase + node];
        const int dg = degs[nodebase + node];
        float acc = 0.f;
        int j = 0;
        for (; j + 4 <= dg; j += 4) {
            int s0 = csr_l[start + j];
            int s1 = csr_l[start + j + 1];
            int s2 = csr_l[start + j + 2];
            int s3 = csr_l[start + j + 3];
            acc += y[s0 * 64 + lane] + y[s1 * 64 + lane]
                 + y[s2 * 64 + lane] + y[s3 * 64 + lane];
        }
        for (; j < dg; j++) acc += y[csr_l[start + j] * 64 + lane];

        float z = frombf(A[(size_t)(nodebase + node) * 128 + 64 + lane]);
        float v = acc * invdeg[nodebase + node] + bias[lane] + z;
        Xout[(size_t)(nodebase + node) * 64 + lane] = fmaxf(v, 0.f);
    }
}

// ---------------- input-side aggregation: M = mean-agg(H) --------------------
__global__ __launch_bounds__(1024) void agg_in(
    const float* __restrict__ H,
    const int* __restrict__ csr_src, const int* __restrict__ rowptr,
    const int* __restrict__ degs, const float* __restrict__ invdeg,
    float* __restrict__ M)
{
    __shared__ float y[NPG * 64];     // 102400 B
    __shared__ int   csr_l[EPG];      // 25600 B
    const int g = blockIdx.x, tid = threadIdx.x;
    const int ebase = g * EPG, nodebase = g * NPG;

    for (int idx = tid; idx < NPG * 16; idx += 1024) {
        int node = idx >> 4, c4 = (idx & 15) * 4;
        *(float4*)&y[node * 64 + c4] =
            *(const float4*)&H[(size_t)(nodebase + node) * 64 + c4];
    }
    for (int e = tid; e < EPG; e += 1024) csr_l[e] = csr_src[ebase + e];
    __syncthreads();

    const int wave = tid >> 6, lane = tid & 63;
    for (int node = wave; node < NPG; node += 16) {
        const int start = rowptr[nodebase + node];
        const int dg = degs[nodebase + node];
        float acc = 0.f;
        int j = 0;
        for (; j + 4 <= dg; j += 4) {
            int s0 = csr_l[start + j];
            int s1 = csr_l[start + j + 1];
            int s2 = csr_l[start + j + 2];
            int s3 = csr_l[start + j + 3];
            acc += y[s0 * 64 + lane] + y[s1 * 64 + lane]
                 + y[s2 * 64 + lane] + y[s3 * 64 + lane];
        }
        for (; j < dg; j++) acc += y[csr_l[start + j] * 64 + lane];

        M[(size_t)(nodebase + node) * 64 + lane] = acc * invdeg[nodebase + node];
    }
}

// ------- score+topk+pool+classifier, LDS-staged (R15-proven) ----------------
__global__ __launch_bounds__(1024) void score_pool3(
    const float* __restrict__ X3,
    const int* __restrict__ esrc, const int* __restrict__ edst,
    const float* __restrict__ Wpr, const float* __restrict__ bpr,
    const float* __restrict__ Wpo,
    const float* __restrict__ Wlin, const float* __restrict__ blin,
    float* __restrict__ out)
{
    __shared__ float y[NPG * 64];        // 102400 B (X3 slice)
    __shared__ float t0s[NPG], ss[NPG], wsel[NPG];
    __shared__ float wprs[64], wpos[64];
    __shared__ float pp[16 * 64];
    __shared__ float pooled[64];
    __shared__ float lgs[2];
    const int g = blockIdx.x, tid = threadIdx.x;
    const int nodebase = g * NPG, ebase = g * EPG;

    if (tid < 64) { wprs[tid] = Wpr[tid]; wpos[tid] = Wpo[tid]; }
    for (int idx = tid; idx < NPG * 16; idx += 1024) {
        int node = idx >> 4, c4 = (idx & 15) * 4;
        *(float4*)&y[node * 64 + c4] =
            *(const float4*)&X3[(size_t)(nodebase + node) * 64 + c4];
    }
    __syncthreads();

    if (tid < NPG) {
        float a0 = 0.f, a1 = 0.f;
        const float* yr = &y[tid * 64];
#pragma unroll
        for (int i = 0; i < 64; i++) {
            int d = (tid + i) & 63;
            float v = yr[d];
            a0 += v * wprs[d];
            a1 += v * wpos[d];
        }
        t0s[tid] = a0;
        ss[tid] = bpr[0] + a1;
    }
    __syncthreads();
    for (int e = tid; e < EPG; e += 1024) {
        int ls = esrc[ebase + e] - nodebase;
        int ld = edst[ebase + e] - nodebase;
        atomicAdd(&ss[ld], t0s[ls]);
    }
    __syncthreads();
    if (tid < NPG) {
        float si = ss[tid];
        int cnt = 0;
        for (int j = 0; j < NPG; j++) {
            float sj = ss[j];
            cnt += (sj > si) || (sj == si && j < tid);
        }
        wsel[tid] = (cnt < KSEL) ? tanhf(si) * (1.f / KSEL) : 0.f;
    }
    __syncthreads();
    {
        const int d = tid & 63, part = tid >> 6;
        float a = 0.f;
        for (int i = part * 25; i < part * 25 + 25; i++)
            a += wsel[i] * y[i * 64 + d];
        pp[part * 64 + d] = a;
    }
    __syncthreads();
    if (tid < 64) {
        float s = 0.f;
#pragma unroll
        for (int i = 0; i < 16; i++) s += pp[i * 64 + tid];
        pooled[tid] = s;
    }
    __syncthreads();
    if (tid < 2) {
        float l = blin[tid];
        for (int d = 0; d < 64; d++) l += pooled[d] * Wlin[d * 2 + tid];
        lgs[tid] = l;
    }
    __syncthreads();
    if (tid < 2) {
        float m = fmaxf(lgs[0], lgs[1]);
        float lse = m + logf(expf(lgs[0] - m) + expf(lgs[1] - m));
        out[g * 2 + tid] = lgs[tid] - lse;
    }
}

extern "C" void kernel_launch(void* const* d_in, const int* in_sizes, int n_in,
                              void* d_out, int out_size, void* d_ws, size_t ws_size,
                              hipStream_t stream) {
    const float* x    = (const float*)d_in[0];
    const int*   eidx = (const int*)d_in[1];
    const float* W1l  = (const float*)d_in[3];
    const float* W1r  = (const float*)d_in[4];
    const float* b1   = (const float*)d_in[5];
    const float* W2l  = (const float*)d_in[6];
    const float* W2r  = (const float*)d_in[7];
    const float* b2   = (const float*)d_in[8];
    const float* W3l  = (const float*)d_in[9];
    const float* W3r  = (const float*)d_in[10];
    const float* b3   = (const float*)d_in[11];
    const float* Wpr  = (const float*)d_in[12];
    const float* bpr  = (const float*)d_in[13];
    const float* Wpo  = (const float*)d_in[14];
    const float* Wlin = (const float*)d_in[15];
    const float* blin = (const float*)d_in[16];

    const int N = in_sizes[0] / F_IN;       // 204800
    const int E = in_sizes[1] / 2;          // 3276800
    const int B = N / NPG;                  // 512
    const int* esrc = eidx;
    const int* edst = eidx + E;

    float* ws = (float*)d_ws;
    unsigned short* A = (unsigned short*)ws;             // [N,128] bf16 yz
    float* P0     = ws + (size_t)N * 64;                 // [N,64]  (A = N*128 ushort = N*64 floats)
    float* P1     = P0 + (size_t)N * 64;                 // [N,64]
    float* Mb     = P1 + (size_t)N * 64;                 // [N,64] mean-agg
    float* invdeg = Mb + (size_t)N * 64;                 // [N]
    short* WF1    = (short*)(invdeg + N);                // 7*8*2*512 shorts
    short* WFc2   = WF1 + 57344;                         // 4*4*2*512 shorts
    short* WFc3   = WFc2 + 16384;
    int*   csr    = (int*)(WFc3 + 16384);                // [E] local src by dst
    int*   rowptr = csr + E;                             // [N]
    int*   degs   = rowptr + N;                          // [N]

    pack_wf<<<(7 * 4096 + 255) / 256, 256, 0, stream>>>(W1l, W1r, WF1, 200, 7);
    pack_wf4<<<(4 * 2048 + 255) / 256, 256, 0, stream>>>(W2l, W2r, WFc2);
    pack_wf4<<<(4 * 2048 + 255) / 256, 256, 0, stream>>>(W3l, W3r, WFc3);

    // CSR once (shared by all layers)
    csr_build<<<B, 256, 0, stream>>>(esrc, edst, csr, rowptr, degs, invdeg);

    // layer 1: yz = x @ [W1l|W1r] -> A (bf16); x1 = relu(agg(y)+b+z) -> P0
    gemm_lds<200, 200, 6, 8><<<N / 128, 256, 0, stream>>>(x, WF1, A);
    agg_lds<<<B, 1024, 0, stream>>>(A, csr, rowptr, degs, invdeg, b1, P0);

    // layer 2 (m-form): M = mean-agg(P0); x2 = relu([M|P0]@Wc2 + b2) + P0 -> P1
    agg_in<<<B, 1024, 0, stream>>>(P0, csr, rowptr, degs, invdeg, Mb);
    combine_ss<<<N / 64, 256, 0, stream>>>(Mb, P0, WFc2, b2, P0, P1);

    // layer 3 (m-form): M = mean-agg(P1); x3 = relu([M|P1]@Wc3 + b3) + P1 -> P0
    agg_in<<<B, 1024, 0, stream>>>(P1, csr, rowptr, degs, invdeg, Mb);
    combine_ss<<<N / 64, 256, 0, stream>>>(Mb, P1, WFc3, b3, P1, P0);

    // score + top-k + pool + classifier (LDS-staged)
    score_pool3<<<B, 1024, 0, stream>>>(P0, esrc, edst,
                                        Wpr, bpr, Wpo, Wlin, blin,
                                        (float*)d_out);
}

// Round 22
// 385.035 us; speedup vs baseline: 1.3222x; 1.0882x over previous
//
#include <hip/hip_runtime.h>
#include <hip/hip_bf16.h>
#include <math.h>

#define F_IN 200
#define HDIM 64
#define NPG  400
#define EPG  6400
#define KSEL 200   // NPG/2

typedef __attribute__((ext_vector_type(4))) float f32x4;
typedef __attribute__((ext_vector_type(8))) short s16x8;
typedef __attribute__((ext_vector_type(4))) unsigned short u16x4;
typedef __attribute__((ext_vector_type(8))) unsigned short u16x8;

__device__ __forceinline__ void gload_lds16(const void* g, void* l) {
    __builtin_amdgcn_global_load_lds(
        (const __attribute__((address_space(1))) void*)g,
        (__attribute__((address_space(3))) void*)l, 16, 0, 0);
}

// RNE float -> bf16 bits
__device__ __forceinline__ unsigned int bf16_rne(float x) {
    unsigned int b = __float_as_uint(x);
    return (b + 0x7FFFu + ((b >> 16) & 1u)) >> 16;
}
__device__ __forceinline__ float frombf(unsigned short u) {
    return __uint_as_float(((unsigned int)u) << 16);
}

// split x into bf16 hi + bf16 lo (x ~= hi + lo, rel err ~2^-17)
__device__ __forceinline__ void split8(f32x4 v0, f32x4 v1, s16x8& h, s16x8& l) {
    float x[8] = {v0.x, v0.y, v0.z, v0.w, v1.x, v1.y, v1.z, v1.w};
#pragma unroll
    for (int j = 0; j < 8; j++) {
        unsigned int hb = bf16_rne(x[j]);
        float hf = __uint_as_float(hb << 16);
        float r = x[j] - hf;
        unsigned int lb = bf16_rne(r);
        h[j] = (short)hb;
        l[j] = (short)lb;
    }
}

// ---------------- pack W ([K,64]|[K,64] fp32) -> fragment-ordered bf16 pairs --
__global__ void pack_wf(const float* __restrict__ Wl, const float* __restrict__ Wr,
                        short* __restrict__ WF, int K, int KC) {
    int idx = blockIdx.x * blockDim.x + threadIdx.x;
    if (idx >= KC * 4096) return;
    int j    = idx & 7;
    int lane = (idx >> 3) & 63;
    int nf   = (idx >> 9) & 7;
    int kc   = idx >> 12;
    int k = kc * 32 + (lane >> 4) * 8 + j;
    int n = nf * 16 + (lane & 15);
    float v = 0.f;
    if (k < K) v = (n < 64) ? Wl[k * 64 + n] : Wr[k * 64 + (n - 64)];
    unsigned int hb = bf16_rne(v);
    float hf = __uint_as_float(hb << 16);
    unsigned int lb = bf16_rne(v - hf);
    WF[(size_t)((kc * 8 + nf) * 2 + 0) * 512 + lane * 8 + j] = (short)hb;
    WF[(size_t)((kc * 8 + nf) * 2 + 1) * 512 + lane * 8 + j] = (short)lb;
}

// ---------------- pack combine-W: [Wl;Wr] (K=128, 4 n-frags) ----------------
__global__ void pack_wf4(const float* __restrict__ Wl, const float* __restrict__ Wr,
                         short* __restrict__ WF) {
    int idx = blockIdx.x * blockDim.x + threadIdx.x;
    if (idx >= 4 * 2048) return;                 // 4 kc x 4 nf x 512
    int j    = idx & 7;
    int lane = (idx >> 3) & 63;
    int nf   = (idx >> 9) & 3;
    int kc   = idx >> 11;
    int k = kc * 32 + (lane >> 4) * 8 + j;
    int n = nf * 16 + (lane & 15);
    float v = (k < 64) ? Wl[k * 64 + n] : Wr[(k - 64) * 64 + n];
    unsigned int hb = bf16_rne(v);
    float hf = __uint_as_float(hb << 16);
    unsigned int lb = bf16_rne(v - hf);
    WF[(size_t)((kc * 4 + nf) * 2 + 0) * 512 + lane * 8 + j] = (short)hb;
    WF[(size_t)((kc * 4 + nf) * 2 + 1) * 512 + lane * 8 + j] = (short)lb;
}

// ---------------- layer-1 MFMA GEMM (R11-proven; bf16 output) ----------------
template <int K, int LDX, int KC, int TAIL>
__global__ __launch_bounds__(256) void gemm_lds(const float* __restrict__ X,
                                                const short* __restrict__ WF,
                                                unsigned short* __restrict__ O) {
    __shared__ float Xs[2][128 * 32];    // 2 x 16 KB
    __shared__ short Ws[2][8 * 2 * 512]; // 2 x 16 KB
    const int tid  = threadIdx.x;
    const int lane = tid & 63;
    const int wave = tid >> 6;
    const size_t rowbase = (size_t)blockIdx.x * 128;
    const f32x4 zero4 = (f32x4){0.f, 0.f, 0.f, 0.f};

    const int srow_off = wave * 32 + (lane >> 3);
    const int sbyte    = 16 * ((lane & 7) ^ (lane >> 3));

#define DMA_CHUNK(b, kc_) {                                                      \
    _Pragma("unroll")                                                            \
    for (int j = 0; j < 4; j++) {                                                \
        const char* xsrc = (const char*)X +                                      \
            (rowbase + srow_off + j * 8) * (size_t)(LDX * 4) + (kc_) * 128 + sbyte; \
        gload_lds16(xsrc, (char*)&Xs[b][0] + wave * 4096 + j * 1024);            \
        const short* wsrc = WF + (size_t)(kc_) * 8192 + wave * 2048 + j * 512 + lane * 8; \
        gload_lds16(wsrc, (char*)&Ws[b][0] + wave * 4096 + j * 1024);            \
    } }

    f32x4 acc[2][8];
#pragma unroll
    for (int m = 0; m < 2; m++)
#pragma unroll
        for (int nf = 0; nf < 8; nf++) acc[m][nf] = zero4;

    DMA_CHUNK(0, 0);
    __syncthreads();

    for (int kc = 0; kc < KC; kc++) {
        const int b = kc & 1;
        if (kc + 1 < KC) DMA_CHUNK(b ^ 1, kc + 1);

        s16x8 ah[2], al[2];
#pragma unroll
        for (int m = 0; m < 2; m++) {
            const int lr = wave * 32 + m * 16 + (lane & 15);
            const int g0 = (lane >> 4) * 2;
            f32x4 v0 = *(const f32x4*)&Xs[b][lr * 32 + 4 * (g0 ^ (lane & 7))];
            f32x4 v1 = *(const f32x4*)&Xs[b][lr * 32 + 4 * ((g0 + 1) ^ (lane & 7))];
            split8(v0, v1, ah[m], al[m]);
        }
#pragma unroll
        for (int nf = 0; nf < 8; nf++) {
            s16x8 wh = *(const s16x8*)&Ws[b][(nf * 2 + 0) * 512 + lane * 8];
            s16x8 wl = *(const s16x8*)&Ws[b][(nf * 2 + 1) * 512 + lane * 8];
#pragma unroll
            for (int m = 0; m < 2; m++) {
                acc[m][nf] = __builtin_amdgcn_mfma_f32_16x16x32_bf16(ah[m], wh, acc[m][nf], 0, 0, 0);
                acc[m][nf] = __builtin_amdgcn_mfma_f32_16x16x32_bf16(al[m], wh, acc[m][nf], 0, 0, 0);
                acc[m][nf] = __builtin_amdgcn_mfma_f32_16x16x32_bf16(ah[m], wl, acc[m][nf], 0, 0, 0);
            }
        }
        __syncthreads();
    }
#undef DMA_CHUNK

    if constexpr (TAIL > 0) {
        s16x8 ah[2], al[2];
#pragma unroll
        for (int m = 0; m < 2; m++) {
            const size_t row = rowbase + wave * 32 + m * 16 + (lane & 15);
            const int k0 = KC * 32 + (lane >> 4) * 8;
            f32x4 v0 = (k0 + 4 <= K) ? *(const f32x4*)&X[row * (size_t)LDX + k0] : zero4;
            f32x4 v1 = (k0 + 8 <= K) ? *(const f32x4*)&X[row * (size_t)LDX + k0 + 4] : zero4;
            split8(v0, v1, ah[m], al[m]);
        }
#pragma unroll
        for (int nf = 0; nf < 8; nf++) {
            s16x8 wh = *(const s16x8*)&WF[(size_t)((KC * 8 + nf) * 2 + 0) * 512 + lane * 8];
            s16x8 wl = *(const s16x8*)&WF[(size_t)((KC * 8 + nf) * 2 + 1) * 512 + lane * 8];
#pragma unroll
            for (int m = 0; m < 2; m++) {
                acc[m][nf] = __builtin_amdgcn_mfma_f32_16x16x32_bf16(ah[m], wh, acc[m][nf], 0, 0, 0);
                acc[m][nf] = __builtin_amdgcn_mfma_f32_16x16x32_bf16(al[m], wh, acc[m][nf], 0, 0, 0);
                acc[m][nf] = __builtin_amdgcn_mfma_f32_16x16x32_bf16(ah[m], wl, acc[m][nf], 0, 0, 0);
            }
        }
    }

    // epilogue: fp32 restage (proven), convert to bf16 on store
    float* cs0 = &Xs[0][wave * 1024];
    float* cs1 = &Xs[1][wave * 1024];
#pragma unroll
    for (int m = 0; m < 2; m++) {
        const int scol = lane & 15;
        const int srow = (lane >> 4) * 4;
#pragma unroll
        for (int nf = 0; nf < 8; nf++)
#pragma unroll
            for (int r = 0; r < 4; r++) {
                int cr = srow + r;
                float* p = (cr < 8) ? cs0 + cr * 128 : cs1 + (cr - 8) * 128;
                p[nf * 16 + scol] = acc[m][nf][r];
            }
#pragma unroll
        for (int ps = 0; ps < 8; ps++) {
            int row = ps * 2 + (lane >> 5);
            int col = (lane & 31) * 4;
            const float* p = (row < 8) ? cs0 + row * 128 : cs1 + (row - 8) * 128;
            f32x4 v = *(const f32x4*)&p[col];
            u16x4 o;
#pragma unroll
            for (int q = 0; q < 4; q++) o[q] = (unsigned short)bf16_rne(v[q]);
            *(u16x4*)&O[(rowbase + wave * 32 + m * 16 + row) * 128 + col] = o;
        }
    }
}

// ------- combine, bf16 activations: P = relu([M|H]@Wc+b) + H (all bf16) ------
// 64 rows/block, 256 thr (4 waves x one 16-row m-frag). A-side activations are
// EXACT bf16 -> fragments loaded directly from global as s16x8 (R7-proven
// addressing), no split-lo, 2 MFMAs per frag. W staged to LDS (R16-proven DMA).
// resid = H (bf16) prefetched early (T14). NO barriers except the one W-DMA sync.
__global__ __launch_bounds__(256) void combine_bf(
    const unsigned short* __restrict__ Mb, const unsigned short* __restrict__ Hb,
    const short* __restrict__ WF, const float* __restrict__ bias,
    unsigned short* __restrict__ P)
{
    __shared__ short Ws[4][4096];        // 32 KB
    __shared__ float Cs[2][4 * 512];     // 16 KB (epilogue restage, wave-private)
    const int tid  = threadIdx.x;
    const int lane = tid & 63;
    const int wave = tid >> 6;
    const size_t rowbase = (size_t)blockIdx.x * 64;

    // ---- T14: prefetch resid (=H) + bias early ----
    f32x4 rr[4], bb;
    {
        const int col = (lane & 15) * 4;
        bb = *(const f32x4*)&bias[col];
#pragma unroll
        for (int i = 0; i < 4; i++) {
            int row = i * 4 + (lane >> 4);
            size_t grow = rowbase + wave * 16 + row;
            u16x4 h4 = *(const u16x4*)&Hb[grow * 64 + col];
#pragma unroll
            for (int q = 0; q < 4; q++) rr[i][q] = frombf(h4[q]);
        }
    }

    // ---- W DMA (R16-proven addressing) ----
#pragma unroll
    for (int c = 0; c < 4; c++)
#pragma unroll
        for (int t = 0; t < 2; t++) {
            int idx = t * 256 + tid;
            const short* wsrc = WF + (size_t)c * 4096 + idx * 8;
            gload_lds16(wsrc, (char*)&Ws[c][0] + idx * 16);
        }

    // ---- A fragments direct from global (exact bf16; R7-proven mapping) ----
    const size_t arow = rowbase + wave * 16 + (lane & 15);
    const int kq = (lane >> 4) * 8;
    s16x8 ah[4];
    ah[0] = *(const s16x8*)&Mb[arow * 64 + kq];
    ah[1] = *(const s16x8*)&Mb[arow * 64 + 32 + kq];
    ah[2] = *(const s16x8*)&Hb[arow * 64 + kq];
    ah[3] = *(const s16x8*)&Hb[arow * 64 + 32 + kq];

    __syncthreads();   // W ready

    f32x4 acc[4];
#pragma unroll
    for (int nf = 0; nf < 4; nf++) acc[nf] = (f32x4){0.f, 0.f, 0.f, 0.f};

#pragma unroll
    for (int kc = 0; kc < 4; kc++) {
#pragma unroll
        for (int nf = 0; nf < 4; nf++) {
            s16x8 wh = *(const s16x8*)&Ws[kc][(nf * 2 + 0) * 512 + lane * 8];
            s16x8 wl = *(const s16x8*)&Ws[kc][(nf * 2 + 1) * 512 + lane * 8];
            acc[nf] = __builtin_amdgcn_mfma_f32_16x16x32_bf16(ah[kc], wh, acc[nf], 0, 0, 0);
            acc[nf] = __builtin_amdgcn_mfma_f32_16x16x32_bf16(ah[kc], wl, acc[nf], 0, 0, 0);
        }
    }

    // ---- epilogue: wave-private restage, fused bias/relu/resid, bf16 store ---
    {
        float* cs0 = &Cs[0][wave * 512];
        float* cs1 = &Cs[1][wave * 512];
        const int scol = lane & 15;
        const int srow = (lane >> 4) * 4;
#pragma unroll
        for (int nf = 0; nf < 4; nf++)
#pragma unroll
            for (int ri = 0; ri < 4; ri++) {
                int cr = srow + ri;
                float* p = (cr < 8) ? cs0 + cr * 64 : cs1 + (cr - 8) * 64;
                p[nf * 16 + scol] = acc[nf][ri];
            }
#pragma unroll
        for (int i = 0; i < 4; i++) {
            int row = i * 4 + (lane >> 4);
            int col = (lane & 15) * 4;
            const float* p = (row < 8) ? cs0 + row * 64 : cs1 + (row - 8) * 64;
            f32x4 v = *(const f32x4*)&p[col];
            size_t grow = rowbase + wave * 16 + row;
            u16x4 o;
#pragma unroll
            for (int q = 0; q < 4; q++)
                o[q] = (unsigned short)bf16_rne(fmaxf(v[q] + bb[q], 0.f) + rr[i][q]);
            *(u16x4*)&P[grow * 64 + col] = o;
        }
    }
}

// ---------------- CSR build: one block per graph ----------------
__global__ __launch_bounds__(256) void csr_build(
    const int* __restrict__ esrc, const int* __restrict__ edst,
    int* __restrict__ csr_src, int* __restrict__ rowptr,
    int* __restrict__ degs, float* __restrict__ invdeg)
{
    __shared__ int cnt[NPG];
    __shared__ int off[NPG];
    __shared__ int cur[NPG];
    const int g = blockIdx.x, tid = threadIdx.x;
    const int ebase = g * EPG, nodebase = g * NPG;
    for (int i = tid; i < NPG; i += 256) cnt[i] = 0;
    __syncthreads();
    for (int e = tid; e < EPG; e += 256)
        atomicAdd(&cnt[edst[ebase + e] - nodebase], 1);
    __syncthreads();
    if (tid == 0) {
        int run = 0;
        for (int i = 0; i < NPG; i++) { off[i] = run; run += cnt[i]; }
    }
    __syncthreads();
    for (int i = tid; i < NPG; i += 256) {
        cur[i] = off[i];
        rowptr[nodebase + i] = off[i];
        degs[nodebase + i] = cnt[i];
        invdeg[nodebase + i] = 1.f / fmaxf((float)cnt[i], 1.f);
    }
    __syncthreads();
    for (int e = tid; e < EPG; e += 256) {
        int ld = edst[ebase + e] - nodebase;
        int p = atomicAdd(&cur[ld], 1);
        csr_src[ebase + p] = esrc[ebase + e] - nodebase;  // local src
    }
}

// ---------------- layer-1 aggregate+combine (bf16 A in, bf16 P out) ----------
__global__ __launch_bounds__(1024) void agg_lds(
    const unsigned short* __restrict__ A,
    const int* __restrict__ csr_src, const int* __restrict__ rowptr,
    const int* __restrict__ degs, const float* __restrict__ invdeg,
    const float* __restrict__ bias,
    unsigned short* __restrict__ Xout)
{
    __shared__ float y[NPG * 64];     // 102400 B
    __shared__ int   csr_l[EPG];      // 25600 B
    const int g = blockIdx.x, tid = threadIdx.x;
    const int ebase = g * EPG, nodebase = g * NPG;

    for (int idx = tid; idx < NPG * 8; idx += 1024) {
        int node = idx >> 3, c8 = (idx & 7) * 8;
        u16x8 v = *(const u16x8*)&A[(size_t)(nodebase + node) * 128 + c8];
#pragma unroll
        for (int q = 0; q < 8; q++) y[node * 64 + c8 + q] = frombf(v[q]);
    }
    for (int e = tid; e < EPG; e += 1024) csr_l[e] = csr_src[ebase + e];
    __syncthreads();

    const int wave = tid >> 6, lane = tid & 63;
    for (int node = wave; node < NPG; node += 16) {
        const int start = rowptr[nodebase + node];
        const int dg = degs[nodebase + node];
        float acc = 0.f;
        int j = 0;
        for (; j + 4 <= dg; j += 4) {
            int s0 = csr_l[start + j];
            int s1 = csr_l[start + j + 1];
            int s2 = csr_l[start + j + 2];
            int s3 = csr_l[start + j + 3];
            acc += y[s0 * 64 + lane] + y[s1 * 64 + lane]
                 + y[s2 * 64 + lane] + y[s3 * 64 + lane];
        }
        for (; j < dg; j++) acc += y[csr_l[start + j] * 64 + lane];

        float z = frombf(A[(size_t)(nodebase + node) * 128 + 64 + lane]);
        float v = acc * invdeg[nodebase + node] + bias[lane] + z;
        Xout[(size_t)(nodebase + node) * 64 + lane] =
            (unsigned short)bf16_rne(fmaxf(v, 0.f));
    }
}

// ---------------- input-side aggregation: M = mean-agg(H), bf16 in/out -------
__global__ __launch_bounds__(1024) void agg_in(
    const unsigned short* __restrict__ H,
    const int* __restrict__ csr_src, const int* __restrict__ rowptr,
    const int* __restrict__ degs, const float* __restrict__ invdeg,
    unsigned short* __restrict__ M)
{
    __shared__ float y[NPG * 64];     // 102400 B
    __shared__ int   csr_l[EPG];      // 25600 B
    const int g = blockIdx.x, tid = threadIdx.x;
    const int ebase = g * EPG, nodebase = g * NPG;

    for (int idx = tid; idx < NPG * 8; idx += 1024) {
        int node = idx >> 3, c8 = (idx & 7) * 8;
        u16x8 v = *(const u16x8*)&H[(size_t)(nodebase + node) * 64 + c8];
#pragma unroll
        for (int q = 0; q < 8; q++) y[node * 64 + c8 + q] = frombf(v[q]);
    }
    for (int e = tid; e < EPG; e += 1024) csr_l[e] = csr_src[ebase + e];
    __syncthreads();

    const int wave = tid >> 6, lane = tid & 63;
    for (int node = wave; node < NPG; node += 16) {
        const int start = rowptr[nodebase + node];
        const int dg = degs[nodebase + node];
        float acc = 0.f;
        int j = 0;
        for (; j + 4 <= dg; j += 4) {
            int s0 = csr_l[start + j];
            int s1 = csr_l[start + j + 1];
            int s2 = csr_l[start + j + 2];
            int s3 = csr_l[start + j + 3];
            acc += y[s0 * 64 + lane] + y[s1 * 64 + lane]
                 + y[s2 * 64 + lane] + y[s3 * 64 + lane];
        }
        for (; j < dg; j++) acc += y[csr_l[start + j] * 64 + lane];

        M[(size_t)(nodebase + node) * 64 + lane] =
            (unsigned short)bf16_rne(acc * invdeg[nodebase + node]);
    }
}

// ------- score+topk+pool+classifier, LDS-staged (R15-proven; bf16 X3) --------
__global__ __launch_bounds__(1024) void score_pool3(
    const unsigned short* __restrict__ X3,
    const int* __restrict__ esrc, const int* __restrict__ edst,
    const float* __restrict__ Wpr, const float* __restrict__ bpr,
    const float* __restrict__ Wpo,
    const float* __restrict__ Wlin, const float* __restrict__ blin,
    float* __restrict__ out)
{
    __shared__ float y[NPG * 64];        // 102400 B (X3 slice)
    __shared__ float t0s[NPG], ss[NPG], wsel[NPG];
    __shared__ float wprs[64], wpos[64];
    __shared__ float pp[16 * 64];
    __shared__ float pooled[64];
    __shared__ float lgs[2];
    const int g = blockIdx.x, tid = threadIdx.x;
    const int nodebase = g * NPG, ebase = g * EPG;

    if (tid < 64) { wprs[tid] = Wpr[tid]; wpos[tid] = Wpo[tid]; }
    for (int idx = tid; idx < NPG * 8; idx += 1024) {
        int node = idx >> 3, c8 = (idx & 7) * 8;
        u16x8 v = *(const u16x8*)&X3[(size_t)(nodebase + node) * 64 + c8];
#pragma unroll
        for (int q = 0; q < 8; q++) y[node * 64 + c8 + q] = frombf(v[q]);
    }
    __syncthreads();

    if (tid < NPG) {
        float a0 = 0.f, a1 = 0.f;
        const float* yr = &y[tid * 64];
#pragma unroll
        for (int i = 0; i < 64; i++) {
            int d = (tid + i) & 63;
            float v = yr[d];
            a0 += v * wprs[d];
            a1 += v * wpos[d];
        }
        t0s[tid] = a0;
        ss[tid] = bpr[0] + a1;
    }
    __syncthreads();
    for (int e = tid; e < EPG; e += 1024) {
        int ls = esrc[ebase + e] - nodebase;
        int ld = edst[ebase + e] - nodebase;
        atomicAdd(&ss[ld], t0s[ls]);
    }
    __syncthreads();
    if (tid < NPG) {
        float si = ss[tid];
        int cnt = 0;
        for (int j = 0; j < NPG; j++) {
            float sj = ss[j];
            cnt += (sj > si) || (sj == si && j < tid);
        }
        wsel[tid] = (cnt < KSEL) ? tanhf(si) * (1.f / KSEL) : 0.f;
    }
    __syncthreads();
    {
        const int d = tid & 63, part = tid >> 6;
        float a = 0.f;
        for (int i = part * 25; i < part * 25 + 25; i++)
            a += wsel[i] * y[i * 64 + d];
        pp[part * 64 + d] = a;
    }
    __syncthreads();
    if (tid < 64) {
        float s = 0.f;
#pragma unroll
        for (int i = 0; i < 16; i++) s += pp[i * 64 + tid];
        pooled[tid] = s;
    }
    __syncthreads();
    if (tid < 2) {
        float l = blin[tid];
        for (int d = 0; d < 64; d++) l += pooled[d] * Wlin[d * 2 + tid];
        lgs[tid] = l;
    }
    __syncthreads();
    if (tid < 2) {
        float m = fmaxf(lgs[0], lgs[1]);
        float lse = m + logf(expf(lgs[0] - m) + expf(lgs[1] - m));
        out[g * 2 + tid] = lgs[tid] - lse;
    }
}

extern "C" void kernel_launch(void* const* d_in, const int* in_sizes, int n_in,
                              void* d_out, int out_size, void* d_ws, size_t ws_size,
                              hipStream_t stream) {
    const float* x    = (const float*)d_in[0];
    const int*   eidx = (const int*)d_in[1];
    const float* W1l  = (const float*)d_in[3];
    const float* W1r  = (const float*)d_in[4];
    const float* b1   = (const float*)d_in[5];
    const float* W2l  = (const float*)d_in[6];
    const float* W2r  = (const float*)d_in[7];
    const float* b2   = (const float*)d_in[8];
    const float* W3l  = (const float*)d_in[9];
    const float* W3r  = (const float*)d_in[10];
    const float* b3   = (const float*)d_in[11];
    const float* Wpr  = (const float*)d_in[12];
    const float* bpr  = (const float*)d_in[13];
    const float* Wpo  = (const float*)d_in[14];
    const float* Wlin = (const float*)d_in[15];
    const float* blin = (const float*)d_in[16];

    const int N = in_sizes[0] / F_IN;       // 204800
    const int E = in_sizes[1] / 2;          // 3276800
    const int B = N / NPG;                  // 512
    const int* esrc = eidx;
    const int* edst = eidx + E;

    float* ws = (float*)d_ws;
    unsigned short* A   = (unsigned short*)ws;           // [N,128] bf16 yz (= N*64 floats)
    unsigned short* P0  = (unsigned short*)(ws + (size_t)N * 64);  // [N,64] bf16
    unsigned short* P1  = P0 + (size_t)N * 64;           // [N,64] bf16
    unsigned short* Mb  = P1 + (size_t)N * 64;           // [N,64] bf16
    float* invdeg = (float*)(Mb + (size_t)N * 64);       // [N]
    short* WF1    = (short*)(invdeg + N);                // 7*8*2*512 shorts
    short* WFc2   = WF1 + 57344;                         // 4*4*2*512 shorts
    short* WFc3   = WFc2 + 16384;
    int*   csr    = (int*)(WFc3 + 16384);                // [E] local src by dst
    int*   rowptr = csr + E;                             // [N]
    int*   degs   = rowptr + N;                          // [N]

    pack_wf<<<(7 * 4096 + 255) / 256, 256, 0, stream>>>(W1l, W1r, WF1, 200, 7);
    pack_wf4<<<(4 * 2048 + 255) / 256, 256, 0, stream>>>(W2l, W2r, WFc2);
    pack_wf4<<<(4 * 2048 + 255) / 256, 256, 0, stream>>>(W3l, W3r, WFc3);

    // CSR once (shared by all layers)
    csr_build<<<B, 256, 0, stream>>>(esrc, edst, csr, rowptr, degs, invdeg);

    // layer 1: yz = x @ [W1l|W1r] -> A (bf16); x1 = relu(agg(y)+b+z) -> P0 (bf16)
    gemm_lds<200, 200, 6, 8><<<N / 128, 256, 0, stream>>>(x, WF1, A);
    agg_lds<<<B, 1024, 0, stream>>>(A, csr, rowptr, degs, invdeg, b1, P0);

    // layer 2 (m-form, bf16): M = mean-agg(P0); x2 = relu([M|P0]@Wc2+b2)+P0 -> P1
    agg_in<<<B, 1024, 0, stream>>>(P0, csr, rowptr, degs, invdeg, Mb);
    combine_bf<<<N / 64, 256, 0, stream>>>(Mb, P0, WFc2, b2, P1);

    // layer 3 (m-form, bf16): M = mean-agg(P1); x3 = relu([M|P1]@Wc3+b3)+P1 -> P0
    agg_in<<<B, 1024, 0, stream>>>(P1, csr, rowptr, degs, invdeg, Mb);
    combine_bf<<<N / 64, 256, 0, stream>>>(Mb, P1, WFc3, b3, P0);

    // score + top-k + pool + classifier (LDS-staged, bf16 input)
    score_pool3<<<B, 1024, 0, stream>>>(P0, esrc, edst,
                                        Wpr, bpr, Wpo, Wlin, blin,
                                        (float*)d_out);
}

// Round 24
// 384.765 us; speedup vs baseline: 1.3231x; 1.0007x over previous
//
#include <hip/hip_runtime.h>
#include <hip/hip_bf16.h>
#include <math.h>

#define F_IN 200
#define HDIM 64
#define NPG  400
#define EPG  6400
#define KSEL 200   // NPG/2

typedef __attribute__((ext_vector_type(4))) float f32x4;
typedef __attribute__((ext_vector_type(8))) short s16x8;
typedef __attribute__((ext_vector_type(4))) unsigned short u16x4;
typedef __attribute__((ext_vector_type(8))) unsigned short u16x8;

__device__ __forceinline__ void gload_lds16(const void* g, void* l) {
    __builtin_amdgcn_global_load_lds(
        (const __attribute__((address_space(1))) void*)g,
        (__attribute__((address_space(3))) void*)l, 16, 0, 0);
}

// RNE float -> bf16 bits
__device__ __forceinline__ unsigned int bf16_rne(float x) {
    unsigned int b = __float_as_uint(x);
    return (b + 0x7FFFu + ((b >> 16) & 1u)) >> 16;
}
__device__ __forceinline__ float frombf(unsigned short u) {
    return __uint_as_float(((unsigned int)u) << 16);
}

// split x into bf16 hi + bf16 lo (x ~= hi + lo, rel err ~2^-17)
__device__ __forceinline__ void split8(f32x4 v0, f32x4 v1, s16x8& h, s16x8& l) {
    float x[8] = {v0.x, v0.y, v0.z, v0.w, v1.x, v1.y, v1.z, v1.w};
#pragma unroll
    for (int j = 0; j < 8; j++) {
        unsigned int hb = bf16_rne(x[j]);
        float hf = __uint_as_float(hb << 16);
        float r = x[j] - hf;
        unsigned int lb = bf16_rne(r);
        h[j] = (short)hb;
        l[j] = (short)lb;
    }
}

// ---------------- pack W ([K,64]|[K,64] fp32) -> fragment-ordered bf16 pairs --
__global__ void pack_wf(const float* __restrict__ Wl, const float* __restrict__ Wr,
                        short* __restrict__ WF, int K, int KC) {
    int idx = blockIdx.x * blockDim.x + threadIdx.x;
    if (idx >= KC * 4096) return;
    int j    = idx & 7;
    int lane = (idx >> 3) & 63;
    int nf   = (idx >> 9) & 7;
    int kc   = idx >> 12;
    int k = kc * 32 + (lane >> 4) * 8 + j;
    int n = nf * 16 + (lane & 15);
    float v = 0.f;
    if (k < K) v = (n < 64) ? Wl[k * 64 + n] : Wr[k * 64 + (n - 64)];
    unsigned int hb = bf16_rne(v);
    float hf = __uint_as_float(hb << 16);
    unsigned int lb = bf16_rne(v - hf);
    WF[(size_t)((kc * 8 + nf) * 2 + 0) * 512 + lane * 8 + j] = (short)hb;
    WF[(size_t)((kc * 8 + nf) * 2 + 1) * 512 + lane * 8 + j] = (short)lb;
}

// ---------------- pack combine-W: [Wl;Wr] (K=128, 4 n-frags) ----------------
__global__ void pack_wf4(const float* __restrict__ Wl, const float* __restrict__ Wr,
                         short* __restrict__ WF) {
    int idx = blockIdx.x * blockDim.x + threadIdx.x;
    if (idx >= 4 * 2048) return;                 // 4 kc x 4 nf x 512
    int j    = idx & 7;
    int lane = (idx >> 3) & 63;
    int nf   = (idx >> 9) & 3;
    int kc   = idx >> 11;
    int k = kc * 32 + (lane >> 4) * 8 + j;
    int n = nf * 16 + (lane & 15);
    float v = (k < 64) ? Wl[k * 64 + n] : Wr[(k - 64) * 64 + n];
    unsigned int hb = bf16_rne(v);
    float hf = __uint_as_float(hb << 16);
    unsigned int lb = bf16_rne(v - hf);
    WF[(size_t)((kc * 4 + nf) * 2 + 0) * 512 + lane * 8 + j] = (short)hb;
    WF[(size_t)((kc * 4 + nf) * 2 + 1) * 512 + lane * 8 + j] = (short)lb;
}

// ---------------- layer-1 MFMA GEMM (R11-proven; bf16 output) ----------------
template <int K, int LDX, int KC, int TAIL>
__global__ __launch_bounds__(256) void gemm_lds(const float* __restrict__ X,
                                                const short* __restrict__ WF,
                                                unsigned short* __restrict__ O) {
    __shared__ float Xs[2][128 * 32];    // 2 x 16 KB
    __shared__ short Ws[2][8 * 2 * 512]; // 2 x 16 KB
    const int tid  = threadIdx.x;
    const int lane = tid & 63;
    const int wave = tid >> 6;
    const size_t rowbase = (size_t)blockIdx.x * 128;
    const f32x4 zero4 = (f32x4){0.f, 0.f, 0.f, 0.f};

    const int srow_off = wave * 32 + (lane >> 3);
    const int sbyte    = 16 * ((lane & 7) ^ (lane >> 3));

#define DMA_CHUNK(b, kc_) {                                                      \
    _Pragma("unroll")                                                            \
    for (int j = 0; j < 4; j++) {                                                \
        const char* xsrc = (const char*)X +                                      \
            (rowbase + srow_off + j * 8) * (size_t)(LDX * 4) + (kc_) * 128 + sbyte; \
        gload_lds16(xsrc, (char*)&Xs[b][0] + wave * 4096 + j * 1024);            \
        const short* wsrc = WF + (size_t)(kc_) * 8192 + wave * 2048 + j * 512 + lane * 8; \
        gload_lds16(wsrc, (char*)&Ws[b][0] + wave * 4096 + j * 1024);            \
    } }

    f32x4 acc[2][8];
#pragma unroll
    for (int m = 0; m < 2; m++)
#pragma unroll
        for (int nf = 0; nf < 8; nf++) acc[m][nf] = zero4;

    DMA_CHUNK(0, 0);
    __syncthreads();

    for (int kc = 0; kc < KC; kc++) {
        const int b = kc & 1;
        if (kc + 1 < KC) DMA_CHUNK(b ^ 1, kc + 1);

        s16x8 ah[2], al[2];
#pragma unroll
        for (int m = 0; m < 2; m++) {
            const int lr = wave * 32 + m * 16 + (lane & 15);
            const int g0 = (lane >> 4) * 2;
            f32x4 v0 = *(const f32x4*)&Xs[b][lr * 32 + 4 * (g0 ^ (lane & 7))];
            f32x4 v1 = *(const f32x4*)&Xs[b][lr * 32 + 4 * ((g0 + 1) ^ (lane & 7))];
            split8(v0, v1, ah[m], al[m]);
        }
#pragma unroll
        for (int nf = 0; nf < 8; nf++) {
            s16x8 wh = *(const s16x8*)&Ws[b][(nf * 2 + 0) * 512 + lane * 8];
            s16x8 wl = *(const s16x8*)&Ws[b][(nf * 2 + 1) * 512 + lane * 8];
#pragma unroll
            for (int m = 0; m < 2; m++) {
                acc[m][nf] = __builtin_amdgcn_mfma_f32_16x16x32_bf16(ah[m], wh, acc[m][nf], 0, 0, 0);
                acc[m][nf] = __builtin_amdgcn_mfma_f32_16x16x32_bf16(al[m], wh, acc[m][nf], 0, 0, 0);
                acc[m][nf] = __builtin_amdgcn_mfma_f32_16x16x32_bf16(ah[m], wl, acc[m][nf], 0, 0, 0);
            }
        }
        __syncthreads();
    }
#undef DMA_CHUNK

    if constexpr (TAIL > 0) {
        s16x8 ah[2], al[2];
#pragma unroll
        for (int m = 0; m < 2; m++) {
            const size_t row = rowbase + wave * 32 + m * 16 + (lane & 15);
            const int k0 = KC * 32 + (lane >> 4) * 8;
            f32x4 v0 = (k0 + 4 <= K) ? *(const f32x4*)&X[row * (size_t)LDX + k0] : zero4;
            f32x4 v1 = (k0 + 8 <= K) ? *(const f32x4*)&X[row * (size_t)LDX + k0 + 4] : zero4;
            split8(v0, v1, ah[m], al[m]);
        }
#pragma unroll
        for (int nf = 0; nf < 8; nf++) {
            s16x8 wh = *(const s16x8*)&WF[(size_t)((KC * 8 + nf) * 2 + 0) * 512 + lane * 8];
            s16x8 wl = *(const s16x8*)&WF[(size_t)((KC * 8 + nf) * 2 + 1) * 512 + lane * 8];
#pragma unroll
            for (int m = 0; m < 2; m++) {
                acc[m][nf] = __builtin_amdgcn_mfma_f32_16x16x32_bf16(ah[m], wh, acc[m][nf], 0, 0, 0);
                acc[m][nf] = __builtin_amdgcn_mfma_f32_16x16x32_bf16(al[m], wh, acc[m][nf], 0, 0, 0);
                acc[m][nf] = __builtin_amdgcn_mfma_f32_16x16x32_bf16(ah[m], wl, acc[m][nf], 0, 0, 0);
            }
        }
    }

    // epilogue: fp32 restage (proven), convert to bf16 on store
    float* cs0 = &Xs[0][wave * 1024];
    float* cs1 = &Xs[1][wave * 1024];
#pragma unroll
    for (int m = 0; m < 2; m++) {
        const int scol = lane & 15;
        const int srow = (lane >> 4) * 4;
#pragma unroll
        for (int nf = 0; nf < 8; nf++)
#pragma unroll
            for (int r = 0; r < 4; r++) {
                int cr = srow + r;
                float* p = (cr < 8) ? cs0 + cr * 128 : cs1 + (cr - 8) * 128;
                p[nf * 16 + scol] = acc[m][nf][r];
            }
#pragma unroll
        for (int ps = 0; ps < 8; ps++) {
            int row = ps * 2 + (lane >> 5);
            int col = (lane & 31) * 4;
            const float* p = (row < 8) ? cs0 + row * 128 : cs1 + (row - 8) * 128;
            f32x4 v = *(const f32x4*)&p[col];
            u16x4 o;
#pragma unroll
            for (int q = 0; q < 4; q++) o[q] = (unsigned short)bf16_rne(v[q]);
            *(u16x4*)&O[(rowbase + wave * 32 + m * 16 + row) * 128 + col] = o;
        }
    }
}

// ------- combine, bf16 activations: P = relu([M|H]@Wc+b) + H (all bf16) ------
// 64 rows/block, 256 thr (4 waves x one 16-row m-frag). A-side activations are
// EXACT bf16 -> fragments loaded directly from global as s16x8 (R7-proven
// addressing), no split-lo, 2 MFMAs per frag. W staged to LDS (R16-proven DMA).
// resid = H (bf16) prefetched early (T14). NO barriers except the one W-DMA sync.
__global__ __launch_bounds__(256) void combine_bf(
    const unsigned short* __restrict__ Mb, const unsigned short* __restrict__ Hb,
    const short* __restrict__ WF, const float* __restrict__ bias,
    unsigned short* __restrict__ P)
{
    __shared__ short Ws[4][4096];        // 32 KB
    __shared__ float Cs[2][4 * 512];     // 16 KB (epilogue restage, wave-private)
    const int tid  = threadIdx.x;
    const int lane = tid & 63;
    const int wave = tid >> 6;
    const size_t rowbase = (size_t)blockIdx.x * 64;

    // ---- T14: prefetch resid (=H) + bias early ----
    f32x4 rr[4], bb;
    {
        const int col = (lane & 15) * 4;
        bb = *(const f32x4*)&bias[col];
#pragma unroll
        for (int i = 0; i < 4; i++) {
            int row = i * 4 + (lane >> 4);
            size_t grow = rowbase + wave * 16 + row;
            u16x4 h4 = *(const u16x4*)&Hb[grow * 64 + col];
#pragma unroll
            for (int q = 0; q < 4; q++) rr[i][q] = frombf(h4[q]);
        }
    }

    // ---- W DMA (R16-proven addressing) ----
#pragma unroll
    for (int c = 0; c < 4; c++)
#pragma unroll
        for (int t = 0; t < 2; t++) {
            int idx = t * 256 + tid;
            const short* wsrc = WF + (size_t)c * 4096 + idx * 8;
            gload_lds16(wsrc, (char*)&Ws[c][0] + idx * 16);
        }

    // ---- A fragments direct from global (exact bf16; R7-proven mapping) ----
    const size_t arow = rowbase + wave * 16 + (lane & 15);
    const int kq = (lane >> 4) * 8;
    s16x8 ah[4];
    ah[0] = *(const s16x8*)&Mb[arow * 64 + kq];
    ah[1] = *(const s16x8*)&Mb[arow * 64 + 32 + kq];
    ah[2] = *(const s16x8*)&Hb[arow * 64 + kq];
    ah[3] = *(const s16x8*)&Hb[arow * 64 + 32 + kq];

    __syncthreads();   // W ready

    f32x4 acc[4];
#pragma unroll
    for (int nf = 0; nf < 4; nf++) acc[nf] = (f32x4){0.f, 0.f, 0.f, 0.f};

#pragma unroll
    for (int kc = 0; kc < 4; kc++) {
#pragma unroll
        for (int nf = 0; nf < 4; nf++) {
            s16x8 wh = *(const s16x8*)&Ws[kc][(nf * 2 + 0) * 512 + lane * 8];
            s16x8 wl = *(const s16x8*)&Ws[kc][(nf * 2 + 1) * 512 + lane * 8];
            acc[nf] = __builtin_amdgcn_mfma_f32_16x16x32_bf16(ah[kc], wh, acc[nf], 0, 0, 0);
            acc[nf] = __builtin_amdgcn_mfma_f32_16x16x32_bf16(ah[kc], wl, acc[nf], 0, 0, 0);
        }
    }

    // ---- epilogue: wave-private restage, fused bias/relu/resid, bf16 store ---
    {
        float* cs0 = &Cs[0][wave * 512];
        float* cs1 = &Cs[1][wave * 512];
        const int scol = lane & 15;
        const int srow = (lane >> 4) * 4;
#pragma unroll
        for (int nf = 0; nf < 4; nf++)
#pragma unroll
            for (int ri = 0; ri < 4; ri++) {
                int cr = srow + ri;
                float* p = (cr < 8) ? cs0 + cr * 64 : cs1 + (cr - 8) * 64;
                p[nf * 16 + scol] = acc[nf][ri];
            }
#pragma unroll
        for (int i = 0; i < 4; i++) {
            int row = i * 4 + (lane >> 4);
            int col = (lane & 15) * 4;
            const float* p = (row < 8) ? cs0 + row * 64 : cs1 + (row - 8) * 64;
            f32x4 v = *(const f32x4*)&p[col];
            size_t grow = rowbase + wave * 16 + row;
            u16x4 o;
#pragma unroll
            for (int q = 0; q < 4; q++)
                o[q] = (unsigned short)bf16_rne(fmaxf(v[q] + bb[q], 0.f) + rr[i][q]);
            *(u16x4*)&P[grow * 64 + col] = o;
        }
    }
}

// ---------------- CSR build: one block per graph ----------------
__global__ __launch_bounds__(256) void csr_build(
    const int* __restrict__ esrc, const int* __restrict__ edst,
    int* __restrict__ csr_src, int* __restrict__ rowptr,
    int* __restrict__ degs, float* __restrict__ invdeg)
{
    __shared__ int cnt[NPG];
    __shared__ int off[NPG];
    __shared__ int cur[NPG];
    const int g = blockIdx.x, tid = threadIdx.x;
    const int ebase = g * EPG, nodebase = g * NPG;
    for (int i = tid; i < NPG; i += 256) cnt[i] = 0;
    __syncthreads();
    for (int e = tid; e < EPG; e += 256)
        atomicAdd(&cnt[edst[ebase + e] - nodebase], 1);
    __syncthreads();
    if (tid == 0) {
        int run = 0;
        for (int i = 0; i < NPG; i++) { off[i] = run; run += cnt[i]; }
    }
    __syncthreads();
    for (int i = tid; i < NPG; i += 256) {
        cur[i] = off[i];
        rowptr[nodebase + i] = off[i];
        degs[nodebase + i] = cnt[i];
        invdeg[nodebase + i] = 1.f / fmaxf((float)cnt[i], 1.f);
    }
    __syncthreads();
    for (int e = tid; e < EPG; e += 256) {
        int ld = edst[ebase + e] - nodebase;
        int p = atomicAdd(&cur[ld], 1);
        csr_src[ebase + p] = esrc[ebase + e] - nodebase;  // local src
    }
}

// ---------------- layer-1 aggregate+combine (bf16 A in, bf16 P out) ----------
__global__ __launch_bounds__(1024) void agg_lds(
    const unsigned short* __restrict__ A,
    const int* __restrict__ csr_src, const int* __restrict__ rowptr,
    const int* __restrict__ degs, const float* __restrict__ invdeg,
    const float* __restrict__ bias,
    unsigned short* __restrict__ Xout)
{
    __shared__ float y[NPG * 64];     // 102400 B
    __shared__ int   csr_l[EPG];      // 25600 B
    const int g = blockIdx.x, tid = threadIdx.x;
    const int ebase = g * EPG, nodebase = g * NPG;

    for (int idx = tid; idx < NPG * 8; idx += 1024) {
        int node = idx >> 3, c8 = (idx & 7) * 8;
        u16x8 v = *(const u16x8*)&A[(size_t)(nodebase + node) * 128 + c8];
#pragma unroll
        for (int q = 0; q < 8; q++) y[node * 64 + c8 + q] = frombf(v[q]);
    }
    for (int e = tid; e < EPG; e += 1024) csr_l[e] = csr_src[ebase + e];
    __syncthreads();

    const int wave = tid >> 6, lane = tid & 63;
    for (int node = wave; node < NPG; node += 16) {
        const int start = rowptr[nodebase + node];
        const int dg = degs[nodebase + node];
        float acc = 0.f;
        int j = 0;
        for (; j + 4 <= dg; j += 4) {
            int s0 = csr_l[start + j];
            int s1 = csr_l[start + j + 1];
            int s2 = csr_l[start + j + 2];
            int s3 = csr_l[start + j + 3];
            acc += y[s0 * 64 + lane] + y[s1 * 64 + lane]
                 + y[s2 * 64 + lane] + y[s3 * 64 + lane];
        }
        for (; j < dg; j++) acc += y[csr_l[start + j] * 64 + lane];

        float z = frombf(A[(size_t)(nodebase + node) * 128 + 64 + lane]);
        float v = acc * invdeg[nodebase + node] + bias[lane] + z;
        Xout[(size_t)(nodebase + node) * 64 + lane] =
            (unsigned short)bf16_rne(fmaxf(v, 0.f));
    }
}

// ---------------- input-side aggregation: M = mean-agg(H), bf16 in/out -------
__global__ __launch_bounds__(1024) void agg_in(
    const unsigned short* __restrict__ H,
    const int* __restrict__ csr_src, const int* __restrict__ rowptr,
    const int* __restrict__ degs, const float* __restrict__ invdeg,
    unsigned short* __restrict__ M)
{
    __shared__ float y[NPG * 64];     // 102400 B
    __shared__ int   csr_l[EPG];      // 25600 B
    const int g = blockIdx.x, tid = threadIdx.x;
    const int ebase = g * EPG, nodebase = g * NPG;

    for (int idx = tid; idx < NPG * 8; idx += 1024) {
        int node = idx >> 3, c8 = (idx & 7) * 8;
        u16x8 v = *(const u16x8*)&H[(size_t)(nodebase + node) * 64 + c8];
#pragma unroll
        for (int q = 0; q < 8; q++) y[node * 64 + c8 + q] = frombf(v[q]);
    }
    for (int e = tid; e < EPG; e += 1024) csr_l[e] = csr_src[ebase + e];
    __syncthreads();

    const int wave = tid >> 6, lane = tid & 63;
    for (int node = wave; node < NPG; node += 16) {
        const int start = rowptr[nodebase + node];
        const int dg = degs[nodebase + node];
        float acc = 0.f;
        int j = 0;
        for (; j + 4 <= dg; j += 4) {
            int s0 = csr_l[start + j];
            int s1 = csr_l[start + j + 1];
            int s2 = csr_l[start + j + 2];
            int s3 = csr_l[start + j + 3];
            acc += y[s0 * 64 + lane] + y[s1 * 64 + lane]
                 + y[s2 * 64 + lane] + y[s3 * 64 + lane];
        }
        for (; j < dg; j++) acc += y[csr_l[start + j] * 64 + lane];

        M[(size_t)(nodebase + node) * 64 + lane] =
            (unsigned short)bf16_rne(acc * invdeg[nodebase + node]);
    }
}

// ------- score+topk+pool+classifier, LDS-staged (R15-proven; bf16 X3) --------
__global__ __launch_bounds__(1024) void score_pool3(
    const unsigned short* __restrict__ X3,
    const int* __restrict__ esrc, const int* __restrict__ edst,
    const float* __restrict__ Wpr, const float* __restrict__ bpr,
    const float* __restrict__ Wpo,
    const float* __restrict__ Wlin, const float* __restrict__ blin,
    float* __restrict__ out)
{
    __shared__ float y[NPG * 64];        // 102400 B (X3 slice)
    __shared__ float t0s[NPG], ss[NPG], wsel[NPG];
    __shared__ float wprs[64], wpos[64];
    __shared__ float pp[16 * 64];
    __shared__ float pooled[64];
    __shared__ float lgs[2];
    const int g = blockIdx.x, tid = threadIdx.x;
    const int nodebase = g * NPG, ebase = g * EPG;

    if (tid < 64) { wprs[tid] = Wpr[tid]; wpos[tid] = Wpo[tid]; }
    for (int idx = tid; idx < NPG * 8; idx += 1024) {
        int node = idx >> 3, c8 = (idx & 7) * 8;
        u16x8 v = *(const u16x8*)&X3[(size_t)(nodebase + node) * 64 + c8];
#pragma unroll
        for (int q = 0; q < 8; q++) y[node * 64 + c8 + q] = frombf(v[q]);
    }
    __syncthreads();

    if (tid < NPG) {
        float a0 = 0.f, a1 = 0.f;
        const float* yr = &y[tid * 64];
#pragma unroll
        for (int i = 0; i < 64; i++) {
            int d = (tid + i) & 63;
            float v = yr[d];
            a0 += v * wprs[d];
            a1 += v * wpos[d];
        }
        t0s[tid] = a0;
        ss[tid] = bpr[0] + a1;
    }
    __syncthreads();
    for (int e = tid; e < EPG; e += 1024) {
        int ls = esrc[ebase + e] - nodebase;
        int ld = edst[ebase + e] - nodebase;
        atomicAdd(&ss[ld], t0s[ls]);
    }
    __syncthreads();
    if (tid < NPG) {
        float si = ss[tid];
        int cnt = 0;
        for (int j = 0; j < NPG; j++) {
            float sj = ss[j];
            cnt += (sj > si) || (sj == si && j < tid);
        }
        wsel[tid] = (cnt < KSEL) ? tanhf(si) * (1.f / KSEL) : 0.f;
    }
    __syncthreads();
    {
        const int d = tid & 63, part = tid >> 6;
        float a = 0.f;
        for (int i = part * 25; i < part * 25 + 25; i++)
            a += wsel[i] * y[i * 64 + d];
        pp[part * 64 + d] = a;
    }
    __syncthreads();
    if (tid < 64) {
        float s = 0.f;
#pragma unroll
        for (int i = 0; i < 16; i++) s += pp[i * 64 + tid];
        pooled[tid] = s;
    }
    __syncthreads();
    if (tid < 2) {
        float l = blin[tid];
        for (int d = 0; d < 64; d++) l += pooled[d] * Wlin[d * 2 + tid];
        lgs[tid] = l;
    }
    __syncthreads();
    if (tid < 2) {
        float m = fmaxf(lgs[0], lgs[1]);
        float lse = m + logf(expf(lgs[0] - m) + expf(lgs[1] - m));
        out[g * 2 + tid] = lgs[tid] - lse;
    }
}

extern "C" void kernel_launch(void* const* d_in, const int* in_sizes, int n_in,
                              void* d_out, int out_size, void* d_ws, size_t ws_size,
                              hipStream_t stream) {
    const float* x    = (const float*)d_in[0];
    const int*   eidx = (const int*)d_in[1];
    const float* W1l  = (const float*)d_in[3];
    const float* W1r  = (const float*)d_in[4];
    const float* b1   = (const float*)d_in[5];
    const float* W2l  = (const float*)d_in[6];
    const float* W2r  = (const float*)d_in[7];
    const float* b2   = (const float*)d_in[8];
    const float* W3l  = (const float*)d_in[9];
    const float* W3r  = (const float*)d_in[10];
    const float* b3   = (const float*)d_in[11];
    const float* Wpr  = (const float*)d_in[12];
    const float* bpr  = (const float*)d_in[13];
    const float* Wpo  = (const float*)d_in[14];
    const float* Wlin = (const float*)d_in[15];
    const float* blin = (const float*)d_in[16];

    const int N = in_sizes[0] / F_IN;       // 204800
    const int E = in_sizes[1] / 2;          // 3276800
    const int B = N / NPG;                  // 512
    const int* esrc = eidx;
    const int* edst = eidx + E;

    float* ws = (float*)d_ws;
    unsigned short* A   = (unsigned short*)ws;           // [N,128] bf16 yz (= N*64 floats)
    unsigned short* P0  = (unsigned short*)(ws + (size_t)N * 64);  // [N,64] bf16
    unsigned short* P1  = P0 + (size_t)N * 64;           // [N,64] bf16
    unsigned short* Mb  = P1 + (size_t)N * 64;           // [N,64] bf16
    float* invdeg = (float*)(Mb + (size_t)N * 64);       // [N]
    short* WF1    = (short*)(invdeg + N);                // 7*8*2*512 shorts
    short* WFc2   = WF1 + 57344;                         // 4*4*2*512 shorts
    short* WFc3   = WFc2 + 16384;
    int*   csr    = (int*)(WFc3 + 16384);                // [E] local src by dst
    int*   rowptr = csr + E;                             // [N]
    int*   degs   = rowptr + N;                          // [N]

    pack_wf<<<(7 * 4096 + 255) / 256, 256, 0, stream>>>(W1l, W1r, WF1, 200, 7);
    pack_wf4<<<(4 * 2048 + 255) / 256, 256, 0, stream>>>(W2l, W2r, WFc2);
    pack_wf4<<<(4 * 2048 + 255) / 256, 256, 0, stream>>>(W3l, W3r, WFc3);

    // CSR once (shared by all layers)
    csr_build<<<B, 256, 0, stream>>>(esrc, edst, csr, rowptr, degs, invdeg);

    // layer 1: yz = x @ [W1l|W1r] -> A (bf16); x1 = relu(agg(y)+b+z) -> P0 (bf16)
    gemm_lds<200, 200, 6, 8><<<N / 128, 256, 0, stream>>>(x, WF1, A);
    agg_lds<<<B, 1024, 0, stream>>>(A, csr, rowptr, degs, invdeg, b1, P0);

    // layer 2 (m-form, bf16): M = mean-agg(P0); x2 = relu([M|P0]@Wc2+b2)+P0 -> P1
    agg_in<<<B, 1024, 0, stream>>>(P0, csr, rowptr, degs, invdeg, Mb);
    combine_bf<<<N / 64, 256, 0, stream>>>(Mb, P0, WFc2, b2, P1);

    // layer 3 (m-form, bf16): M = mean-agg(P1); x3 = relu([M|P1]@Wc3+b3)+P1 -> P0
    agg_in<<<B, 1024, 0, stream>>>(P1, csr, rowptr, degs, invdeg, Mb);
    combine_bf<<<N / 64, 256, 0, stream>>>(Mb, P1, WFc3, b3, P0);

    // score + top-k + pool + classifier (LDS-staged, bf16 input)
    score_pool3<<<B, 1024, 0, stream>>>(P0, esrc, edst,
                                        Wpr, bpr, Wpo, Wlin, blin,
                                        (float*)d_out);
}